// Round 2
// baseline (376.929 us; speedup 1.0000x reference)
//
#include <hip/hip_runtime.h>

// TreeModel: soft decision tree forward. B=8192, D=E=256, H=50 (pad 64),
// 31 inner nodes, 32 leaves. MFMA fp16 16x16x32, fp32 accum/epilogues.

#define B_ROWS 8192
#define HDIM 50
#define HPAD 64

typedef _Float16 f16;
typedef _Float16 f16x8 __attribute__((ext_vector_type(8)));
typedef _Float16 f16x4 __attribute__((ext_vector_type(4)));
typedef float f32x4 __attribute__((ext_vector_type(4)));

static __device__ __forceinline__ f32x4 mfma16(f16x8 a, f16x8 b, f32x4 c) {
  return __builtin_amdgcn_mfma_f32_16x16x32_f16(a, b, c, 0, 0, 0);
}

// ---------------- prep: fp32 -> fp16 cast (vector) ----------------
__global__ void k_cast_f16(const float* __restrict__ in, f16* __restrict__ out, int n4) {
  int i = blockIdx.x * blockDim.x + threadIdx.x;
  if (i < n4) {
    float4 v = reinterpret_cast<const float4*>(in)[i];
    f16x4 o = { (f16)v.x, (f16)v.y, (f16)v.z, (f16)v.w };
    reinterpret_cast<f16x4*>(out)[i] = o;
  }
}

// ---------------- prep: batched transpose-cast with zero pad ----------------
// in: [S][R][C] fp32 ; out: [S][Cp][Rp] fp16, out[s][c][r] = (r<R && c<C) ? in[s][r][c] : 0
__global__ void k_tcast(const float* __restrict__ in, f16* __restrict__ out,
                        int R, int C, int Rp, int Cp) {
  __shared__ float t[32][33];
  const int s = blockIdx.z;
  const int r0 = blockIdx.x * 32, c0 = blockIdx.y * 32;
  const int tx = threadIdx.x, ty = threadIdx.y;
  const float* ip = in + (size_t)s * R * C;
  f16* op = out + (size_t)s * Cp * Rp;
#pragma unroll
  for (int i = 0; i < 4; ++i) {
    int r = r0 + ty + 8 * i, c = c0 + tx;
    t[ty + 8 * i][tx] = (r < R && c < C) ? ip[(size_t)r * C + c] : 0.f;
  }
  __syncthreads();
#pragma unroll
  for (int i = 0; i < 4; ++i) {
    int c = c0 + ty + 8 * i, r = r0 + tx;
    if (c < Cp && r < Rp) op[(size_t)c * Rp + r] = (f16)t[tx][ty + 8 * i];
  }
}

// ---------------- fused 4-layer encoder ----------------
// block = 32 rows x 256 cols; act ping-pong in LDS; weights staged per K-tile.
__global__ __launch_bounds__(256) void k_enc4(const float* __restrict__ x,
    const f16* __restrict__ encWT, const float* __restrict__ enc_b,
    f16* __restrict__ emb) {
  __shared__ f16 act[2][32][264];
  __shared__ f16 Bt[256][72];
  const int tid = threadIdx.x;
  const int wave = tid >> 6, lane = tid & 63;
  const int grp = lane >> 4, lid = lane & 15;
  const int row0 = blockIdx.x * 32;
  const int sr = tid >> 3, sc = (tid & 7) * 8;

  // stage x -> act[0] (cast f32->f16)
  {
    const int xr = tid >> 3, xc = (tid & 7) * 32;
    const float* src = x + (size_t)(row0 + xr) * 256 + xc;
#pragma unroll
    for (int j = 0; j < 4; ++j) {
      float4 a = ((const float4*)src)[2 * j];
      float4 b = ((const float4*)src)[2 * j + 1];
      f16x8 o = { (f16)a.x, (f16)a.y, (f16)a.z, (f16)a.w,
                  (f16)b.x, (f16)b.y, (f16)b.z, (f16)b.w };
      *(f16x8*)&act[0][xr][xc + 8 * j] = o;
    }
  }
  __syncthreads();

  for (int l = 0; l < 4; ++l) {
    const int cur = l & 1, nxt = cur ^ 1;
    f32x4 acc[2][4] = {};
    for (int kt = 0; kt < 4; ++kt) {
#pragma unroll
      for (int p = 0; p < 8; ++p)
        *(f16x8*)&Bt[p * 32 + sr][sc] =
            *(const f16x8*)&encWT[(size_t)l * 65536 + (size_t)(p * 32 + sr) * 256 + kt * 64 + sc];
      __syncthreads();
#pragma unroll
      for (int kk = 0; kk < 2; ++kk) {
        f16x8 af[2], bf[4];
#pragma unroll
        for (int m = 0; m < 2; ++m)
          af[m] = *(const f16x8*)&act[cur][m * 16 + lid][kt * 64 + kk * 32 + grp * 8];
#pragma unroll
        for (int n = 0; n < 4; ++n)
          bf[n] = *(const f16x8*)&Bt[wave * 64 + n * 16 + lid][kk * 32 + grp * 8];
#pragma unroll
        for (int m = 0; m < 2; ++m)
#pragma unroll
          for (int n = 0; n < 4; ++n) acc[m][n] = mfma16(af[m], bf[n], acc[m][n]);
      }
      __syncthreads();
    }
#pragma unroll
    for (int n = 0; n < 4; ++n) {
      const int col = wave * 64 + n * 16 + lid;
      const float bv = enc_b[l * 256 + col];
#pragma unroll
      for (int m = 0; m < 2; ++m)
#pragma unroll
        for (int r = 0; r < 4; ++r) {
          float v = acc[m][n][r] + bv;
          act[nxt][m * 16 + grp * 4 + r][col] = (f16)(v > 0.f ? v : 0.f);
        }
    }
    __syncthreads();
  }
  // final activation is in act[0]
  {
    const int xr = tid >> 3, xc = (tid & 7) * 32;
#pragma unroll
    for (int j = 0; j < 4; ++j)
      *(f16x8*)&emb[(size_t)(row0 + xr) * 256 + xc + 8 * j] =
          *(const f16x8*)&act[0][xr][xc + 8 * j];
  }
}

// ---------------- fused inner nodes: h = relu(emb@W1+b1); logits = h@Ww+bw;
// softmax; t = softmax.x; pR = sigmoid(beta*(t+b)).  64 rows x 1 node per block.
__global__ __launch_bounds__(256) void k_inner(const f16* __restrict__ emb,
    const f16* __restrict__ W1T_all, const float* __restrict__ b1_all,
    const f16* __restrict__ WwT_all, const f16* __restrict__ x_h,
    const float* __restrict__ bw_all, const float* __restrict__ Wb_all,
    const float* __restrict__ bb_all, const float* __restrict__ Wbeta_all,
    const float* __restrict__ bbeta_all, float* __restrict__ pR) {
  __shared__ __align__(16) char u_mem[64 * 264 * 2];   // union: {At,B1t} then xt
  f16 (*At)[72]   = (f16(*)[72])u_mem;                 // [64][72]
  f16 (*B1t)[72]  = (f16(*)[72])(u_mem + 64 * 72 * 2); // [64][72]
  f16 (*xt)[264]  = (f16(*)[264])u_mem;                // [64][264]
  __shared__ f16 ht[64][72];
  __shared__ float red[4][64][2];
  __shared__ float bbuf[64], betabuf[64];

  const int tid = threadIdx.x;
  const int wave = tid >> 6, lane = tid & 63;
  const int grp = lane >> 4, lid = lane & 15;
  const int row0 = blockIdx.x * 64;
  const int node = blockIdx.y;
  const f16* W1T = W1T_all + (size_t)node * HPAD * 256;  // [64][256]
  const f16* WwT = WwT_all + (size_t)node * 256 * HPAD;  // [256][64]
  const int sr = tid >> 3, sc = (tid & 7) * 8;

  // preload Ww B-fragments from L2 (hidden under GEMM1)
  f16x8 bwf[2][4];
#pragma unroll
  for (int kk = 0; kk < 2; ++kk)
#pragma unroll
    for (int n = 0; n < 4; ++n)
      bwf[kk][n] = *(const f16x8*)&WwT[(size_t)(wave * 64 + n * 16 + lid) * HPAD + kk * 32 + grp * 8];

  // ---- GEMM1: h = relu(emb @ W1 + b1), 64 rows x 64 cols, K=256 ----
  f32x4 acc1[4] = {};
  for (int kt = 0; kt < 4; ++kt) {
    const int kb = kt * 64;
#pragma unroll
    for (int p = 0; p < 2; ++p)
      *(f16x8*)&At[p * 32 + sr][sc] =
          *(const f16x8*)&emb[(size_t)(row0 + p * 32 + sr) * 256 + kb + sc];
#pragma unroll
    for (int p = 0; p < 2; ++p)
      *(f16x8*)&B1t[p * 32 + sr][sc] =
          *(const f16x8*)&W1T[(size_t)(p * 32 + sr) * 256 + kb + sc];
    __syncthreads();
#pragma unroll
    for (int kk = 0; kk < 2; ++kk) {
      f16x8 b1f = *(const f16x8*)&B1t[wave * 16 + lid][kk * 32 + grp * 8];
#pragma unroll
      for (int m = 0; m < 4; ++m) {
        f16x8 a1f = *(const f16x8*)&At[m * 16 + lid][kk * 32 + grp * 8];
        acc1[m] = mfma16(a1f, b1f, acc1[m]);
      }
    }
    __syncthreads();
  }
  // h epilogue -> ht LDS
  {
    const int col = wave * 16 + lid;
    const float bv = (col < HDIM) ? b1_all[node * HDIM + col] : 0.f;
#pragma unroll
    for (int m = 0; m < 4; ++m)
#pragma unroll
      for (int r = 0; r < 4; ++r) {
        float v = acc1[m][r] + bv;
        ht[m * 16 + grp * 4 + r][col] = (f16)(v > 0.f ? v : 0.f);
      }
  }
  // stage x tile into union region (safe: post K-loop sync)
  {
    const int xr = tid >> 2, xc0 = (tid & 3) * 64;
#pragma unroll
    for (int j = 0; j < 8; ++j)
      *(f16x8*)&xt[xr][xc0 + 8 * j] =
          *(const f16x8*)&x_h[(size_t)(row0 + xr) * 256 + xc0 + 8 * j];
  }
  __syncthreads();

  // b/beta dots: 4 threads per row over 64 (padded) h cols
  {
    const int row = tid >> 2, q = tid & 3;
    float sb = 0.f, sbt = 0.f;
#pragma unroll
    for (int j = 0; j < 16; ++j) {
      const int c = q * 16 + j;
      if (c < HDIM) {
        float hv = (float)ht[row][c];
        sb  += hv * Wb_all[node * HDIM + c];
        sbt += hv * Wbeta_all[node * HDIM + c];
      }
    }
    sb  += __shfl_xor(sb, 1, 64);  sb  += __shfl_xor(sb, 2, 64);
    sbt += __shfl_xor(sbt, 1, 64); sbt += __shfl_xor(sbt, 2, 64);
    if (q == 0) { bbuf[row] = sb + bb_all[node]; betabuf[row] = sbt + bbeta_all[node]; }
  }

  // ---- GEMM2: logits = h @ Ww, 64 rows x 256 cols, K=64 ----
  f32x4 acc2[4][4] = {};
#pragma unroll
  for (int kk = 0; kk < 2; ++kk) {
    f16x8 af[4];
#pragma unroll
    for (int m = 0; m < 4; ++m) af[m] = *(const f16x8*)&ht[m * 16 + lid][kk * 32 + grp * 8];
#pragma unroll
    for (int m = 0; m < 4; ++m)
#pragma unroll
      for (int n = 0; n < 4; ++n) acc2[m][n] = mfma16(af[m], bwf[kk][n], acc2[m][n]);
  }
  // + bw
#pragma unroll
  for (int n = 0; n < 4; ++n) {
    const int col = wave * 64 + n * 16 + lid;
    const float bwv = bw_all[node * 256 + col];
#pragma unroll
    for (int m = 0; m < 4; ++m)
#pragma unroll
      for (int r = 0; r < 4; ++r) acc2[m][n][r] += bwv;
  }
  // row max over 256 cols
  float rm[16];
#pragma unroll
  for (int m = 0; m < 4; ++m)
#pragma unroll
    for (int r = 0; r < 4; ++r)
      rm[m * 4 + r] = fmaxf(fmaxf(acc2[m][0][r], acc2[m][1][r]),
                            fmaxf(acc2[m][2][r], acc2[m][3][r]));
#pragma unroll
  for (int mask = 1; mask < 16; mask <<= 1)
#pragma unroll
    for (int i = 0; i < 16; ++i) rm[i] = fmaxf(rm[i], __shfl_xor(rm[i], mask, 64));
  if (lid == 0)
#pragma unroll
    for (int m = 0; m < 4; ++m)
#pragma unroll
      for (int r = 0; r < 4; ++r) red[wave][m * 16 + grp * 4 + r][0] = rm[m * 4 + r];
  __syncthreads();
#pragma unroll
  for (int m = 0; m < 4; ++m)
#pragma unroll
    for (int r = 0; r < 4; ++r) {
      const int row = m * 16 + grp * 4 + r;
      rm[m * 4 + r] = fmaxf(fmaxf(red[0][row][0], red[1][row][0]),
                            fmaxf(red[2][row][0], red[3][row][0]));
    }
  __syncthreads();
  // exp, sum, dot with x
  float s[16], dt[16];
#pragma unroll
  for (int i = 0; i < 16; ++i) { s[i] = 0.f; dt[i] = 0.f; }
#pragma unroll
  for (int m = 0; m < 4; ++m)
#pragma unroll
    for (int r = 0; r < 4; ++r) {
      const int row = m * 16 + grp * 4 + r;
#pragma unroll
      for (int n = 0; n < 4; ++n) {
        const int col = wave * 64 + n * 16 + lid;
        float e = __expf(acc2[m][n][r] - rm[m * 4 + r]);
        s[m * 4 + r] += e;
        dt[m * 4 + r] += e * (float)xt[row][col];
      }
    }
#pragma unroll
  for (int mask = 1; mask < 16; mask <<= 1)
#pragma unroll
    for (int i = 0; i < 16; ++i) {
      s[i] += __shfl_xor(s[i], mask, 64);
      dt[i] += __shfl_xor(dt[i], mask, 64);
    }
  if (lid == 0)
#pragma unroll
    for (int m = 0; m < 4; ++m)
#pragma unroll
      for (int r = 0; r < 4; ++r) {
        red[wave][m * 16 + grp * 4 + r][0] = s[m * 4 + r];
        red[wave][m * 16 + grp * 4 + r][1] = dt[m * 4 + r];
      }
  __syncthreads();
  if (tid < 64) {
    float S  = red[0][tid][0] + red[1][tid][0] + red[2][tid][0] + red[3][tid][0];
    float DT = red[0][tid][1] + red[1][tid][1] + red[2][tid][1] + red[3][tid][1];
    float z = betabuf[tid] * (DT / S + bbuf[tid]);
    pR[(size_t)(row0 + tid) * 32 + node] = 1.f / (1.f + __expf(-z));
  }
}

// ---------------- leaf: y_leaf[row][leaf] = relu(emb @ lfW1[l] + b1) . W2 + b2 ----
// 128 rows x 256 cols per block.
__global__ __launch_bounds__(256) void k_leaf(const f16* __restrict__ emb,
    const f16* __restrict__ W1T_all, const float* __restrict__ b1_all,
    const float* __restrict__ W2_all, const float* __restrict__ b2_all,
    float* __restrict__ y_leaf) {
  __shared__ f16 At[128][72];
  __shared__ f16 Bt[256][72];
  __shared__ float red[4][128];
  const int tid = threadIdx.x;
  const int wave = tid >> 6, lane = tid & 63;
  const int grp = lane >> 4, lid = lane & 15;
  const int row0 = blockIdx.x * 128;
  const int leaf = blockIdx.y;
  const f16* WT = W1T_all + (size_t)leaf * 65536;
  const float* b1 = b1_all + leaf * 256;
  const float* W2 = W2_all + leaf * 256;
  const int sr = tid >> 3, sc = (tid & 7) * 8;

  f32x4 acc[8][4] = {};
  for (int kt = 0; kt < 4; ++kt) {
    const int kb = kt * 64;
#pragma unroll
    for (int p = 0; p < 4; ++p)
      *(f16x8*)&At[p * 32 + sr][sc] =
          *(const f16x8*)&emb[(size_t)(row0 + p * 32 + sr) * 256 + kb + sc];
#pragma unroll
    for (int p = 0; p < 8; ++p)
      *(f16x8*)&Bt[p * 32 + sr][sc] =
          *(const f16x8*)&WT[(size_t)(p * 32 + sr) * 256 + kb + sc];
    __syncthreads();
#pragma unroll
    for (int kk = 0; kk < 2; ++kk) {
      f16x8 af[8], bf[4];
#pragma unroll
      for (int m = 0; m < 8; ++m) af[m] = *(const f16x8*)&At[m * 16 + lid][kk * 32 + grp * 8];
#pragma unroll
      for (int n = 0; n < 4; ++n) bf[n] = *(const f16x8*)&Bt[wave * 64 + n * 16 + lid][kk * 32 + grp * 8];
#pragma unroll
      for (int m = 0; m < 8; ++m)
#pragma unroll
        for (int n = 0; n < 4; ++n) acc[m][n] = mfma16(af[m], bf[n], acc[m][n]);
    }
    __syncthreads();
  }
  // epilogue: relu(acc+b1)*W2, reduce over 256 cols
  float rs[32];
#pragma unroll
  for (int i = 0; i < 32; ++i) rs[i] = 0.f;
#pragma unroll
  for (int n = 0; n < 4; ++n) {
    const int col = wave * 64 + n * 16 + lid;
    const float bv = b1[col];
    const float w2 = W2[col];
#pragma unroll
    for (int m = 0; m < 8; ++m)
#pragma unroll
      for (int r = 0; r < 4; ++r) {
        float v = acc[m][n][r] + bv;
        v = v > 0.f ? v : 0.f;
        rs[m * 4 + r] += v * w2;
      }
  }
#pragma unroll
  for (int mask = 1; mask < 16; mask <<= 1)
#pragma unroll
    for (int i = 0; i < 32; ++i) rs[i] += __shfl_xor(rs[i], mask, 64);
  if (lid == 0)
#pragma unroll
    for (int m = 0; m < 8; ++m)
#pragma unroll
      for (int r = 0; r < 4; ++r) red[wave][m * 16 + grp * 4 + r] = rs[m * 4 + r];
  __syncthreads();
  if (tid < 128) {
    float y = red[0][tid] + red[1][tid] + red[2][tid] + red[3][tid] + b2_all[leaf];
    y_leaf[(size_t)(row0 + tid) * 32 + leaf] = y;
  }
}

// ---------------- combine: heap walk over 31 gates, weighted sum of 32 leaves ----
__global__ void k_combine(const float* __restrict__ pR, const float* __restrict__ y_leaf,
                          float* __restrict__ out) {
  const int b = blockIdx.x * 256 + threadIdx.x;
  float p[32], y[32];
  const float4* pp = (const float4*)(pR + (size_t)b * 32);
  const float4* yp = (const float4*)(y_leaf + (size_t)b * 32);
#pragma unroll
  for (int i = 0; i < 8; ++i) {
    float4 v = pp[i]; p[i*4] = v.x; p[i*4+1] = v.y; p[i*4+2] = v.z; p[i*4+3] = v.w;
    float4 w = yp[i]; y[i*4] = w.x; y[i*4+1] = w.y; y[i*4+2] = w.z; y[i*4+3] = w.w;
  }
  float o = 0.f;
#pragma unroll
  for (int l = 0; l < 32; ++l) {
    float pr = 1.f;
    int node = 0;
#pragma unroll
    for (int k = 0; k < 5; ++k) {
      const int bit = (l >> (4 - k)) & 1;
      const float pv = p[node];
      pr *= bit ? pv : (1.f - pv);
      node = 2 * node + 1 + bit;
    }
    o += pr * y[l];
  }
  out[b] = o;
}

extern "C" void kernel_launch(void* const* d_in, const int* in_sizes, int n_in,
                              void* d_out, int out_size, void* d_ws, size_t ws_size,
                              hipStream_t stream) {
  (void)in_sizes; (void)n_in; (void)out_size; (void)ws_size;
  const float* x        = (const float*)d_in[0];
  const float* enc_W    = (const float*)d_in[1];
  const float* enc_b    = (const float*)d_in[2];
  const float* in_W1    = (const float*)d_in[3];
  const float* in_b1    = (const float*)d_in[4];
  const float* in_Ww    = (const float*)d_in[5];
  const float* in_bw    = (const float*)d_in[6];
  const float* in_Wb    = (const float*)d_in[7];
  const float* in_bb    = (const float*)d_in[8];
  const float* in_Wbeta = (const float*)d_in[9];
  const float* in_bbeta = (const float*)d_in[10];
  const float* lf_W1    = (const float*)d_in[11];
  const float* lf_b1    = (const float*)d_in[12];
  const float* lf_W2    = (const float*)d_in[13];
  const float* lf_b2    = (const float*)d_in[14];
  float* out = (float*)d_out;

  char* ws = (char*)d_ws;
  f16* x_h     = (f16*)(ws);                 // 8192*256*2   = 4 MB
  f16* emb     = (f16*)(ws + 4194304);       // 4 MB
  f16* encWT   = (f16*)(ws + 8388608);       // 4*256*256*2  = 512 KB
  f16* lfW1T   = (f16*)(ws + 8912896);       // 32*256*256*2 = 4 MB
  f16* inW1T   = (f16*)(ws + 13107200);      // 31*64*256*2
  f16* inWwT   = (f16*)(ws + 14123008);      // 31*256*64*2
  float* pR    = (float*)(ws + 15138816);    // 8192*32*4 = 1 MB
  float* y_leaf= (float*)(ws + 16187392);    // 8192*32*4 = 1 MB

  dim3 tb(32, 8);
  hipLaunchKernelGGL(k_cast_f16, dim3(2048), dim3(256), 0, stream, x, x_h, B_ROWS * 256 / 4);
  hipLaunchKernelGGL(k_tcast, dim3(8, 8, 4),  tb, 0, stream, enc_W, encWT, 256, 256, 256, 256);
  hipLaunchKernelGGL(k_tcast, dim3(8, 8, 32), tb, 0, stream, lf_W1, lfW1T, 256, 256, 256, 256);
  hipLaunchKernelGGL(k_tcast, dim3(8, 2, 31), tb, 0, stream, in_W1, inW1T, 256, 50, 256, 64);
  hipLaunchKernelGGL(k_tcast, dim3(2, 8, 31), tb, 0, stream, in_Ww, inWwT, 50, 256, 64, 256);

  hipLaunchKernelGGL(k_enc4, dim3(256), dim3(256), 0, stream, x, encWT, enc_b, emb);
  hipLaunchKernelGGL(k_inner, dim3(128, 31), dim3(256), 0, stream, emb, inW1T, in_b1,
                     inWwT, x_h, in_bw, in_Wb, in_bb, in_Wbeta, in_bbeta, pR);
  hipLaunchKernelGGL(k_leaf, dim3(64, 32), dim3(256), 0, stream, emb, lfW1T, lf_b1, lf_W2, lf_b2, y_leaf);
  hipLaunchKernelGGL(k_combine, dim3(32), dim3(256), 0, stream, pR, y_leaf, out);
}

// Round 3
// 285.972 us; speedup vs baseline: 1.3181x; 1.3181x over previous
//
#include <hip/hip_runtime.h>

// TreeModel: soft decision tree forward. B=8192, D=E=256, H=50 (pad 64),
// 31 inner nodes, 32 leaves. MFMA fp16 16x16x32, fp32 accum/epilogues.

#define B_ROWS 8192
#define HDIM 50
#define HPAD 64

typedef _Float16 f16;
typedef _Float16 f16x8 __attribute__((ext_vector_type(8)));
typedef _Float16 f16x4 __attribute__((ext_vector_type(4)));
typedef float f32x4 __attribute__((ext_vector_type(4)));

static __device__ __forceinline__ f32x4 mfma16(f16x8 a, f16x8 b, f32x4 c) {
  return __builtin_amdgcn_mfma_f32_16x16x32_f16(a, b, c, 0, 0, 0);
}

// ---------------- prep: fp32 -> fp16 cast (vector) ----------------
__global__ void k_cast_f16(const float* __restrict__ in, f16* __restrict__ out, int n4) {
  int i = blockIdx.x * blockDim.x + threadIdx.x;
  if (i < n4) {
    float4 v = reinterpret_cast<const float4*>(in)[i];
    f16x4 o = { (f16)v.x, (f16)v.y, (f16)v.z, (f16)v.w };
    reinterpret_cast<f16x4*>(out)[i] = o;
  }
}

// ---------------- prep: batched transpose-cast with zero pad ----------------
// in: [S][R][C] fp32 ; out: [S][Cp][Rp] fp16, out[s][c][r] = (r<R && c<C) ? in[s][r][c] : 0
__global__ void k_tcast(const float* __restrict__ in, f16* __restrict__ out,
                        int R, int C, int Rp, int Cp) {
  __shared__ float t[32][33];
  const int s = blockIdx.z;
  const int r0 = blockIdx.x * 32, c0 = blockIdx.y * 32;
  const int tx = threadIdx.x, ty = threadIdx.y;
  const float* ip = in + (size_t)s * R * C;
  f16* op = out + (size_t)s * Cp * Rp;
#pragma unroll
  for (int i = 0; i < 4; ++i) {
    int r = r0 + ty + 8 * i, c = c0 + tx;
    t[ty + 8 * i][tx] = (r < R && c < C) ? ip[(size_t)r * C + c] : 0.f;
  }
  __syncthreads();
#pragma unroll
  for (int i = 0; i < 4; ++i) {
    int c = c0 + ty + 8 * i, r = r0 + tx;
    if (c < Cp && r < Rp) op[(size_t)c * Rp + r] = (f16)t[tx][ty + 8 * i];
  }
}

// ---------------- fused 4-layer encoder ----------------
__global__ __launch_bounds__(256) void k_enc4(const float* __restrict__ x,
    const f16* __restrict__ encWT, const float* __restrict__ enc_b,
    f16* __restrict__ emb) {
  __shared__ f16 act[2][32][264];
  __shared__ f16 Bt[256][72];
  const int tid = threadIdx.x;
  const int wave = tid >> 6, lane = tid & 63;
  const int grp = lane >> 4, lid = lane & 15;
  const int row0 = blockIdx.x * 32;
  const int sr = tid >> 3, sc = (tid & 7) * 8;

  {
    const int xr = tid >> 3, xc = (tid & 7) * 32;
    const float* src = x + (size_t)(row0 + xr) * 256 + xc;
#pragma unroll
    for (int j = 0; j < 4; ++j) {
      float4 a = ((const float4*)src)[2 * j];
      float4 b = ((const float4*)src)[2 * j + 1];
      f16x8 o = { (f16)a.x, (f16)a.y, (f16)a.z, (f16)a.w,
                  (f16)b.x, (f16)b.y, (f16)b.z, (f16)b.w };
      *(f16x8*)&act[0][xr][xc + 8 * j] = o;
    }
  }
  __syncthreads();

  for (int l = 0; l < 4; ++l) {
    const int cur = l & 1, nxt = cur ^ 1;
    f32x4 acc[2][4] = {};
    for (int kt = 0; kt < 4; ++kt) {
#pragma unroll
      for (int p = 0; p < 8; ++p)
        *(f16x8*)&Bt[p * 32 + sr][sc] =
            *(const f16x8*)&encWT[(size_t)l * 65536 + (size_t)(p * 32 + sr) * 256 + kt * 64 + sc];
      __syncthreads();
#pragma unroll
      for (int kk = 0; kk < 2; ++kk) {
        f16x8 af[2], bf[4];
#pragma unroll
        for (int m = 0; m < 2; ++m)
          af[m] = *(const f16x8*)&act[cur][m * 16 + lid][kt * 64 + kk * 32 + grp * 8];
#pragma unroll
        for (int n = 0; n < 4; ++n)
          bf[n] = *(const f16x8*)&Bt[wave * 64 + n * 16 + lid][kk * 32 + grp * 8];
#pragma unroll
        for (int m = 0; m < 2; ++m)
#pragma unroll
          for (int n = 0; n < 4; ++n) acc[m][n] = mfma16(af[m], bf[n], acc[m][n]);
      }
      __syncthreads();
    }
#pragma unroll
    for (int n = 0; n < 4; ++n) {
      const int col = wave * 64 + n * 16 + lid;
      const float bv = enc_b[l * 256 + col];
#pragma unroll
      for (int m = 0; m < 2; ++m)
#pragma unroll
        for (int r = 0; r < 4; ++r) {
          float v = acc[m][n][r] + bv;
          act[nxt][m * 16 + grp * 4 + r][col] = (f16)(v > 0.f ? v : 0.f);
        }
    }
    __syncthreads();
  }
  {
    const int xr = tid >> 3, xc = (tid & 7) * 32;
#pragma unroll
    for (int j = 0; j < 4; ++j)
      *(f16x8*)&emb[(size_t)(row0 + xr) * 256 + xc + 8 * j] =
          *(const f16x8*)&act[0][xr][xc + 8 * j];
  }
}

// ---------------- fused inner node (64 rows x 1 node), reg-prefetch GEMM1,
// softmax without max-subtraction (safe: logits O(+-5)) ----------------
__global__ __launch_bounds__(256) void k_inner(const f16* __restrict__ emb,
    const f16* __restrict__ W1T_all, const float* __restrict__ b1_all,
    const f16* __restrict__ WwT_all, const f16* __restrict__ x_h,
    const float* __restrict__ bw_all, const float* __restrict__ Wb_all,
    const float* __restrict__ bb_all, const float* __restrict__ Wbeta_all,
    const float* __restrict__ bbeta_all, float* __restrict__ pR) {
  __shared__ __align__(16) char u_mem[64 * 264 * 2];   // union: {At,B1t} then xt
  f16 (*At)[72]   = (f16(*)[72])u_mem;                 // [64][72]
  f16 (*B1t)[72]  = (f16(*)[72])(u_mem + 64 * 72 * 2); // [64][72]
  f16 (*xt)[264]  = (f16(*)[264])u_mem;                // [64][264]
  __shared__ f16 ht[64][72];
  __shared__ float red[4][64][2];
  __shared__ float bbuf[64], betabuf[64];

  const int tid = threadIdx.x;
  const int wave = tid >> 6, lane = tid & 63;
  const int grp = lane >> 4, lid = lane & 15;
  const int row0 = blockIdx.x * 64;
  const int node = blockIdx.y;
  const f16* W1T = W1T_all + (size_t)node * HPAD * 256;  // [64][256]
  const f16* WwT = WwT_all + (size_t)node * 256 * HPAD;  // [256][64]

  // preload Ww B-fragments from L2 (hidden under GEMM1)
  f16x8 bwf[2][4];
#pragma unroll
  for (int kk = 0; kk < 2; ++kk)
#pragma unroll
    for (int n = 0; n < 4; ++n)
      bwf[kk][n] = *(const f16x8*)&WwT[(size_t)(wave * 64 + n * 16 + lid) * HPAD + kk * 32 + grp * 8];

  // ---- GEMM1: h = relu(emb @ W1 + b1), 64x64, K=256, reg-prefetch ----
  const int ar = tid >> 2, ac = (tid & 3) * 16;
  const f16* Ag  = emb + (size_t)(row0 + ar) * 256 + ac;
  const f16* B1g = W1T + (size_t)ar * 256 + ac;
  f16x8 a0, a1, w0, w1;
  a0 = *(const f16x8*)(Ag + 0);  a1 = *(const f16x8*)(Ag + 8);
  w0 = *(const f16x8*)(B1g + 0); w1 = *(const f16x8*)(B1g + 8);

  f32x4 acc1[4] = {};
  for (int kt = 0; kt < 4; ++kt) {
    *(f16x8*)&At[ar][ac] = a0;  *(f16x8*)&At[ar][ac + 8] = a1;
    *(f16x8*)&B1t[ar][ac] = w0; *(f16x8*)&B1t[ar][ac + 8] = w1;
    __syncthreads();
    if (kt < 3) {
      const int kb = (kt + 1) * 64;
      a0 = *(const f16x8*)(Ag + kb);  a1 = *(const f16x8*)(Ag + kb + 8);
      w0 = *(const f16x8*)(B1g + kb); w1 = *(const f16x8*)(B1g + kb + 8);
    }
#pragma unroll
    for (int kk = 0; kk < 2; ++kk) {
      f16x8 b1f = *(const f16x8*)&B1t[wave * 16 + lid][kk * 32 + grp * 8];
#pragma unroll
      for (int m = 0; m < 4; ++m) {
        f16x8 a1f = *(const f16x8*)&At[m * 16 + lid][kk * 32 + grp * 8];
        acc1[m] = mfma16(a1f, b1f, acc1[m]);
      }
    }
    __syncthreads();
  }
  // h epilogue -> ht LDS
  {
    const int col = wave * 16 + lid;
    const float bv = (col < HDIM) ? b1_all[node * HDIM + col] : 0.f;
#pragma unroll
    for (int m = 0; m < 4; ++m)
#pragma unroll
      for (int r = 0; r < 4; ++r) {
        float v = acc1[m][r] + bv;
        ht[m * 16 + grp * 4 + r][col] = (f16)(v > 0.f ? v : 0.f);
      }
  }
  // stage x tile into union region (safe: post K-loop sync)
  {
    const int xr = tid >> 2, xc0 = (tid & 3) * 64;
#pragma unroll
    for (int j = 0; j < 8; ++j)
      *(f16x8*)&xt[xr][xc0 + 8 * j] =
          *(const f16x8*)&x_h[(size_t)(row0 + xr) * 256 + xc0 + 8 * j];
  }
  __syncthreads();

  // b/beta dots: 4 threads per row
  {
    const int row = tid >> 2, q = tid & 3;
    float sb = 0.f, sbt = 0.f;
#pragma unroll
    for (int j = 0; j < 16; ++j) {
      const int c = q * 16 + j;
      if (c < HDIM) {
        float hv = (float)ht[row][c];
        sb  += hv * Wb_all[node * HDIM + c];
        sbt += hv * Wbeta_all[node * HDIM + c];
      }
    }
    sb  += __shfl_xor(sb, 1, 64);  sb  += __shfl_xor(sb, 2, 64);
    sbt += __shfl_xor(sbt, 1, 64); sbt += __shfl_xor(sbt, 2, 64);
    if (q == 0) { bbuf[row] = sb + bb_all[node]; betabuf[row] = sbt + bbeta_all[node]; }
  }

  // ---- GEMM2: logits = h @ Ww + bw, 64x256, K=64 ----
  f32x4 acc2[4][4] = {};
#pragma unroll
  for (int kk = 0; kk < 2; ++kk) {
    f16x8 af[4];
#pragma unroll
    for (int m = 0; m < 4; ++m) af[m] = *(const f16x8*)&ht[m * 16 + lid][kk * 32 + grp * 8];
#pragma unroll
    for (int m = 0; m < 4; ++m)
#pragma unroll
      for (int n = 0; n < 4; ++n) acc2[m][n] = mfma16(af[m], bwf[kk][n], acc2[m][n]);
  }
  // exp (no max-subtract), sum, dot with x
  float s[16], dt[16];
#pragma unroll
  for (int i = 0; i < 16; ++i) { s[i] = 0.f; dt[i] = 0.f; }
#pragma unroll
  for (int n = 0; n < 4; ++n) {
    const int col = wave * 64 + n * 16 + lid;
    const float bwv = bw_all[node * 256 + col];
#pragma unroll
    for (int m = 0; m < 4; ++m)
#pragma unroll
      for (int r = 0; r < 4; ++r) {
        const int row = m * 16 + grp * 4 + r;
        float e = __expf(acc2[m][n][r] + bwv);
        s[m * 4 + r] += e;
        dt[m * 4 + r] += e * (float)xt[row][col];
      }
  }
#pragma unroll
  for (int mask = 1; mask < 16; mask <<= 1)
#pragma unroll
    for (int i = 0; i < 16; ++i) {
      s[i] += __shfl_xor(s[i], mask, 64);
      dt[i] += __shfl_xor(dt[i], mask, 64);
    }
  if (lid == 0)
#pragma unroll
    for (int m = 0; m < 4; ++m)
#pragma unroll
      for (int r = 0; r < 4; ++r) {
        red[wave][m * 16 + grp * 4 + r][0] = s[m * 4 + r];
        red[wave][m * 16 + grp * 4 + r][1] = dt[m * 4 + r];
      }
  __syncthreads();
  if (tid < 64) {
    float S  = red[0][tid][0] + red[1][tid][0] + red[2][tid][0] + red[3][tid][0];
    float DT = red[0][tid][1] + red[1][tid][1] + red[2][tid][1] + red[3][tid][1];
    float z = betabuf[tid] * (DT / S + bbuf[tid]);
    pR[(size_t)(row0 + tid) * 32 + node] = 1.f / (1.f + __expf(-z));
  }
}

// ---------------- leaf: 8-wave (2x4), 128 rows x 256 cols, reg-prefetch ----
__global__ __launch_bounds__(512) void k_leaf(const f16* __restrict__ emb,
    const f16* __restrict__ W1T_all, const float* __restrict__ b1_all,
    const float* __restrict__ W2_all, const float* __restrict__ b2_all,
    float* __restrict__ y_leaf) {
  __shared__ f16 At[128][72];
  __shared__ f16 Bt[256][72];
  __shared__ float red[8][128];
  const int tid = threadIdx.x;
  const int wave = tid >> 6, lane = tid & 63;
  const int wm = wave >> 2, wn = wave & 3;
  const int grp = lane >> 4, lid = lane & 15;
  const int row0 = blockIdx.x * 128;
  const int leaf = blockIdx.y;
  const f16* WT = W1T_all + (size_t)leaf * 65536;
  const float* b1 = b1_all + leaf * 256;
  const float* W2 = W2_all + leaf * 256;

  const int ar = tid >> 2, ac = (tid & 3) * 16;   // A: 128 rows, 32B/thread
  const int br = tid >> 1, bc = (tid & 1) * 32;   // B: 256 rows, 64B/thread
  const f16* Ag = emb + (size_t)(row0 + ar) * 256 + ac;
  const f16* Bg = WT + (size_t)br * 256 + bc;

  f16x8 a0, a1, b0, b1r, b2r, b3r;
  a0 = *(const f16x8*)(Ag + 0);  a1 = *(const f16x8*)(Ag + 8);
  b0 = *(const f16x8*)(Bg + 0);  b1r = *(const f16x8*)(Bg + 8);
  b2r = *(const f16x8*)(Bg + 16); b3r = *(const f16x8*)(Bg + 24);

  f32x4 acc[4][4] = {};
  for (int kt = 0; kt < 4; ++kt) {
    *(f16x8*)&At[ar][ac] = a0;      *(f16x8*)&At[ar][ac + 8] = a1;
    *(f16x8*)&Bt[br][bc] = b0;      *(f16x8*)&Bt[br][bc + 8] = b1r;
    *(f16x8*)&Bt[br][bc + 16] = b2r; *(f16x8*)&Bt[br][bc + 24] = b3r;
    __syncthreads();
    if (kt < 3) {
      const int kb = (kt + 1) * 64;
      a0 = *(const f16x8*)(Ag + kb);      a1 = *(const f16x8*)(Ag + kb + 8);
      b0 = *(const f16x8*)(Bg + kb);      b1r = *(const f16x8*)(Bg + kb + 8);
      b2r = *(const f16x8*)(Bg + kb + 16); b3r = *(const f16x8*)(Bg + kb + 24);
    }
#pragma unroll
    for (int kk = 0; kk < 2; ++kk) {
      f16x8 af[4], bf[4];
#pragma unroll
      for (int m = 0; m < 4; ++m)
        af[m] = *(const f16x8*)&At[wm * 64 + m * 16 + lid][kk * 32 + grp * 8];
#pragma unroll
      for (int n = 0; n < 4; ++n)
        bf[n] = *(const f16x8*)&Bt[wn * 64 + n * 16 + lid][kk * 32 + grp * 8];
#pragma unroll
      for (int m = 0; m < 4; ++m)
#pragma unroll
        for (int n = 0; n < 4; ++n) acc[m][n] = mfma16(af[m], bf[n], acc[m][n]);
    }
    __syncthreads();
  }
  // epilogue: relu(acc+b1)*W2, reduce over this wave's 64 cols
  float rs[16];
#pragma unroll
  for (int i = 0; i < 16; ++i) rs[i] = 0.f;
#pragma unroll
  for (int n = 0; n < 4; ++n) {
    const int col = wn * 64 + n * 16 + lid;
    const float bv = b1[col];
    const float w2 = W2[col];
#pragma unroll
    for (int m = 0; m < 4; ++m)
#pragma unroll
      for (int r = 0; r < 4; ++r) {
        float v = acc[m][n][r] + bv;
        v = v > 0.f ? v : 0.f;
        rs[m * 4 + r] += v * w2;
      }
  }
#pragma unroll
  for (int mask = 1; mask < 16; mask <<= 1)
#pragma unroll
    for (int i = 0; i < 16; ++i) rs[i] += __shfl_xor(rs[i], mask, 64);
  if (lid == 0)
#pragma unroll
    for (int m = 0; m < 4; ++m)
#pragma unroll
      for (int r = 0; r < 4; ++r)
        red[wave][wm * 64 + m * 16 + grp * 4 + r] = rs[m * 4 + r];
  __syncthreads();
  if (tid < 128) {
    const int wmi = tid >> 6;
    float y = red[wmi * 4 + 0][tid] + red[wmi * 4 + 1][tid] +
              red[wmi * 4 + 2][tid] + red[wmi * 4 + 3][tid] + b2_all[leaf];
    y_leaf[(size_t)(row0 + tid) * 32 + leaf] = y;
  }
}

// ---------------- combine ----------------
__global__ void k_combine(const float* __restrict__ pR, const float* __restrict__ y_leaf,
                          float* __restrict__ out) {
  const int b = blockIdx.x * 256 + threadIdx.x;
  float p[32], y[32];
  const float4* pp = (const float4*)(pR + (size_t)b * 32);
  const float4* yp = (const float4*)(y_leaf + (size_t)b * 32);
#pragma unroll
  for (int i = 0; i < 8; ++i) {
    float4 v = pp[i]; p[i*4] = v.x; p[i*4+1] = v.y; p[i*4+2] = v.z; p[i*4+3] = v.w;
    float4 w = yp[i]; y[i*4] = w.x; y[i*4+1] = w.y; y[i*4+2] = w.z; y[i*4+3] = w.w;
  }
  float o = 0.f;
#pragma unroll
  for (int l = 0; l < 32; ++l) {
    float pr = 1.f;
    int node = 0;
#pragma unroll
    for (int k = 0; k < 5; ++k) {
      const int bit = (l >> (4 - k)) & 1;
      const float pv = p[node];
      pr *= bit ? pv : (1.f - pv);
      node = 2 * node + 1 + bit;
    }
    o += pr * y[l];
  }
  out[b] = o;
}

extern "C" void kernel_launch(void* const* d_in, const int* in_sizes, int n_in,
                              void* d_out, int out_size, void* d_ws, size_t ws_size,
                              hipStream_t stream) {
  (void)in_sizes; (void)n_in; (void)out_size; (void)ws_size;
  const float* x        = (const float*)d_in[0];
  const float* enc_W    = (const float*)d_in[1];
  const float* enc_b    = (const float*)d_in[2];
  const float* in_W1    = (const float*)d_in[3];
  const float* in_b1    = (const float*)d_in[4];
  const float* in_Ww    = (const float*)d_in[5];
  const float* in_bw    = (const float*)d_in[6];
  const float* in_Wb    = (const float*)d_in[7];
  const float* in_bb    = (const float*)d_in[8];
  const float* in_Wbeta = (const float*)d_in[9];
  const float* in_bbeta = (const float*)d_in[10];
  const float* lf_W1    = (const float*)d_in[11];
  const float* lf_b1    = (const float*)d_in[12];
  const float* lf_W2    = (const float*)d_in[13];
  const float* lf_b2    = (const float*)d_in[14];
  float* out = (float*)d_out;

  char* ws = (char*)d_ws;
  f16* x_h     = (f16*)(ws);                 // 4 MB
  f16* emb     = (f16*)(ws + 4194304);       // 4 MB
  f16* encWT   = (f16*)(ws + 8388608);       // 512 KB
  f16* lfW1T   = (f16*)(ws + 8912896);       // 4 MB
  f16* inW1T   = (f16*)(ws + 13107200);
  f16* inWwT   = (f16*)(ws + 14123008);
  float* pR    = (float*)(ws + 15138816);
  float* y_leaf= (float*)(ws + 16187392);

  dim3 tb(32, 8);
  hipLaunchKernelGGL(k_cast_f16, dim3(2048), dim3(256), 0, stream, x, x_h, B_ROWS * 256 / 4);
  hipLaunchKernelGGL(k_tcast, dim3(8, 8, 4),  tb, 0, stream, enc_W, encWT, 256, 256, 256, 256);
  hipLaunchKernelGGL(k_tcast, dim3(8, 8, 32), tb, 0, stream, lf_W1, lfW1T, 256, 256, 256, 256);
  hipLaunchKernelGGL(k_tcast, dim3(8, 2, 31), tb, 0, stream, in_W1, inW1T, 256, 50, 256, 64);
  hipLaunchKernelGGL(k_tcast, dim3(2, 8, 31), tb, 0, stream, in_Ww, inWwT, 50, 256, 64, 256);

  hipLaunchKernelGGL(k_enc4, dim3(256), dim3(256), 0, stream, x, encWT, enc_b, emb);
  hipLaunchKernelGGL(k_inner, dim3(128, 31), dim3(256), 0, stream, emb, inW1T, in_b1,
                     inWwT, x_h, in_bw, in_Wb, in_bb, in_Wbeta, in_bbeta, pR);
  hipLaunchKernelGGL(k_leaf, dim3(64, 32), dim3(512), 0, stream, emb, lfW1T, lf_b1, lf_W2, lf_b2, y_leaf);
  hipLaunchKernelGGL(k_combine, dim3(32), dim3(256), 0, stream, pR, y_leaf, out);
}

// Round 5
// 252.146 us; speedup vs baseline: 1.4949x; 1.1342x over previous
//
#include <hip/hip_runtime.h>

// TreeModel: soft decision tree forward. B=8192, D=E=256, H=50 (pad 64),
// 31 inner nodes, 32 leaves. MFMA fp16 16x16x32, fp32 accum/epilogues.

#define B_ROWS 8192
#define HDIM 50
#define HPAD 64

typedef _Float16 f16;
typedef _Float16 f16x8 __attribute__((ext_vector_type(8)));
typedef _Float16 f16x4 __attribute__((ext_vector_type(4)));
typedef float f32x4 __attribute__((ext_vector_type(4)));

static __device__ __forceinline__ f32x4 mfma16(f16x8 a, f16x8 b, f32x4 c) {
  // D[i][j] += sum_k a_frag[i][k] * b_frag[j][k]; i = grp*4+reg, j = lid.
  return __builtin_amdgcn_mfma_f32_16x16x32_f16(a, b, c, 0, 0, 0);
}

// async global->LDS, 16B per lane; lds base must be wave-uniform.
static __device__ __forceinline__ void gload16(const void* g, void* l) {
  __builtin_amdgcn_global_load_lds(
      (const __attribute__((address_space(1))) unsigned int*)g,
      (__attribute__((address_space(3))) unsigned int*)l, 16, 0, 0);
}

// ---------------- prep: fp32 -> fp16 cast (vector) ----------------
__global__ void k_cast_f16(const float* __restrict__ in, f16* __restrict__ out, int n4) {
  int i = blockIdx.x * blockDim.x + threadIdx.x;
  if (i < n4) {
    float4 v = reinterpret_cast<const float4*>(in)[i];
    f16x4 o = { (f16)v.x, (f16)v.y, (f16)v.z, (f16)v.w };
    reinterpret_cast<f16x4*>(out)[i] = o;
  }
}

// ---------------- prep: batched transpose-cast with zero pad ----------------
__global__ void k_tcast(const float* __restrict__ in, f16* __restrict__ out,
                        int R, int C, int Rp, int Cp) {
  __shared__ float t[32][33];
  const int s = blockIdx.z;
  const int r0 = blockIdx.x * 32, c0 = blockIdx.y * 32;
  const int tx = threadIdx.x, ty = threadIdx.y;
  const float* ip = in + (size_t)s * R * C;
  f16* op = out + (size_t)s * Cp * Rp;
#pragma unroll
  for (int i = 0; i < 4; ++i) {
    int r = r0 + ty + 8 * i, c = c0 + tx;
    t[ty + 8 * i][tx] = (r < R && c < C) ? ip[(size_t)r * C + c] : 0.f;
  }
  __syncthreads();
#pragma unroll
  for (int i = 0; i < 4; ++i) {
    int c = c0 + ty + 8 * i, r = r0 + tx;
    if (c < Cp && r < Rp) op[(size_t)c * Rp + r] = (f16)t[tx][ty + 8 * i];
  }
}

// ---------------- fused 4-layer encoder (unchanged) ----------------
__global__ __launch_bounds__(256) void k_enc4(const float* __restrict__ x,
    const f16* __restrict__ encWT, const float* __restrict__ enc_b,
    f16* __restrict__ emb) {
  __shared__ f16 act[2][32][264];
  __shared__ f16 Bt[256][72];
  const int tid = threadIdx.x;
  const int wave = tid >> 6, lane = tid & 63;
  const int grp = lane >> 4, lid = lane & 15;
  const int row0 = blockIdx.x * 32;
  const int sr = tid >> 3, sc = (tid & 7) * 8;

  {
    const int xr = tid >> 3, xc = (tid & 7) * 32;
    const float* src = x + (size_t)(row0 + xr) * 256 + xc;
#pragma unroll
    for (int j = 0; j < 4; ++j) {
      float4 a = ((const float4*)src)[2 * j];
      float4 b = ((const float4*)src)[2 * j + 1];
      f16x8 o = { (f16)a.x, (f16)a.y, (f16)a.z, (f16)a.w,
                  (f16)b.x, (f16)b.y, (f16)b.z, (f16)b.w };
      *(f16x8*)&act[0][xr][xc + 8 * j] = o;
    }
  }
  __syncthreads();

  for (int l = 0; l < 4; ++l) {
    const int cur = l & 1, nxt = cur ^ 1;
    f32x4 acc[2][4] = {};
    for (int kt = 0; kt < 4; ++kt) {
#pragma unroll
      for (int p = 0; p < 8; ++p)
        *(f16x8*)&Bt[p * 32 + sr][sc] =
            *(const f16x8*)&encWT[(size_t)l * 65536 + (size_t)(p * 32 + sr) * 256 + kt * 64 + sc];
      __syncthreads();
#pragma unroll
      for (int kk = 0; kk < 2; ++kk) {
        f16x8 af[2], bf[4];
#pragma unroll
        for (int m = 0; m < 2; ++m)
          af[m] = *(const f16x8*)&act[cur][m * 16 + lid][kt * 64 + kk * 32 + grp * 8];
#pragma unroll
        for (int n = 0; n < 4; ++n)
          bf[n] = *(const f16x8*)&Bt[wave * 64 + n * 16 + lid][kk * 32 + grp * 8];
#pragma unroll
        for (int m = 0; m < 2; ++m)
#pragma unroll
          for (int n = 0; n < 4; ++n) acc[m][n] = mfma16(af[m], bf[n], acc[m][n]);
      }
      __syncthreads();
    }
#pragma unroll
    for (int n = 0; n < 4; ++n) {
      const int col = wave * 64 + n * 16 + lid;
      const float bv = enc_b[l * 256 + col];
#pragma unroll
      for (int m = 0; m < 2; ++m)
#pragma unroll
        for (int r = 0; r < 4; ++r) {
          float v = acc[m][n][r] + bv;
          act[nxt][m * 16 + grp * 4 + r][col] = (f16)(v > 0.f ? v : 0.f);
        }
    }
    __syncthreads();
  }
  {
    const int xr = tid >> 3, xc = (tid & 7) * 32;
#pragma unroll
    for (int j = 0; j < 4; ++j)
      *(f16x8*)&emb[(size_t)(row0 + xr) * 256 + xc + 8 * j] =
          *(const f16x8*)&act[0][xr][xc + 8 * j];
  }
}

// ---------------- fused inner node (64 rows x 1 node) ----------------
// GEMM1 transposed-out -> vectorized ht writes; GEMM2 transposed-out
// (lane holds 4 consecutive logits per batch row) -> x dot via global f16x4.
__global__ __launch_bounds__(256) void k_inner(const f16* __restrict__ emb,
    const f16* __restrict__ W1T_all, const float* __restrict__ b1_all,
    const f16* __restrict__ WwT_all, const f16* __restrict__ x_h,
    const float* __restrict__ bw_all, const float* __restrict__ Wb_all,
    const float* __restrict__ bb_all, const float* __restrict__ Wbeta_all,
    const float* __restrict__ bbeta_all, float* __restrict__ pR) {
  __shared__ f16 At[64][72];
  __shared__ f16 B1t[64][72];
  __shared__ f16 ht[64][72];
  __shared__ float red[4][64][2];
  __shared__ float red2[4][64][2];
  __shared__ float bbuf[64], betabuf[64];

  const int tid = threadIdx.x;
  const int wave = tid >> 6, lane = tid & 63;
  const int grp = lane >> 4, lid = lane & 15;
  const int row0 = blockIdx.x * 64;
  const int node = blockIdx.y;
  const f16* W1T = W1T_all + (size_t)node * HPAD * 256;  // [64][256]
  const f16* WwT = WwT_all + (size_t)node * 256 * HPAD;  // [256][64]

  // preload Ww fragments: bwf[kk][lb] covers logits wave*64+lb*16
  f16x8 bwf[2][4];
#pragma unroll
  for (int kk = 0; kk < 2; ++kk)
#pragma unroll
    for (int lb = 0; lb < 4; ++lb)
      bwf[kk][lb] = *(const f16x8*)&WwT[(size_t)(wave * 64 + lb * 16 + lid) * HPAD + kk * 32 + grp * 8];

  // ---- GEMM1 (transposed out): h^T tiles; reg-prefetch staging ----
  const int ar = tid >> 2, ac = (tid & 3) * 16;
  const f16* Ag  = emb + (size_t)(row0 + ar) * 256 + ac;
  const f16* B1g = W1T + (size_t)ar * 256 + ac;
  f16x8 a0, a1, w0, w1;
  a0 = *(const f16x8*)(Ag + 0);  a1 = *(const f16x8*)(Ag + 8);
  w0 = *(const f16x8*)(B1g + 0); w1 = *(const f16x8*)(B1g + 8);

  f32x4 acc1t[4] = {};   // [m: batch block]; i-axis = hdim, j-axis = batch
  for (int kt = 0; kt < 4; ++kt) {
    *(f16x8*)&At[ar][ac] = a0;  *(f16x8*)&At[ar][ac + 8] = a1;
    *(f16x8*)&B1t[ar][ac] = w0; *(f16x8*)&B1t[ar][ac + 8] = w1;
    __syncthreads();
    if (kt < 3) {
      const int kb = (kt + 1) * 64;
      a0 = *(const f16x8*)(Ag + kb);  a1 = *(const f16x8*)(Ag + kb + 8);
      w0 = *(const f16x8*)(B1g + kb); w1 = *(const f16x8*)(B1g + kb + 8);
    }
#pragma unroll
    for (int kk = 0; kk < 2; ++kk) {
      f16x8 b1f = *(const f16x8*)&B1t[wave * 16 + lid][kk * 32 + grp * 8];
#pragma unroll
      for (int m = 0; m < 4; ++m) {
        f16x8 a1f = *(const f16x8*)&At[m * 16 + lid][kk * 32 + grp * 8];
        acc1t[m] = mfma16(b1f, a1f, acc1t[m]);   // transposed: hdim x batch
      }
    }
    __syncthreads();
  }
  // h epilogue: lane holds hdim {wave*16+grp*4+r} for batch row {m*16+lid}
  {
    const int hc = wave * 16 + grp * 4;
    float bva[4];
#pragma unroll
    for (int r = 0; r < 4; ++r) {
      const int c = hc + r;
      bva[r] = (c < HDIM) ? b1_all[node * HDIM + c] : 0.f;
    }
#pragma unroll
    for (int m = 0; m < 4; ++m) {
      f16x4 hv;
#pragma unroll
      for (int r = 0; r < 4; ++r) {
        float v = acc1t[m][r] + bva[r];
        hv[r] = (f16)(v > 0.f ? v : 0.f);
      }
      *(f16x4*)&ht[m * 16 + lid][hc] = hv;
    }
  }
  __syncthreads();

  // x fragments from global (L2-hot), matching transposed GEMM2 layout
  f16x4 xv[4][4];  // [lb][bb]
#pragma unroll
  for (int lb = 0; lb < 4; ++lb)
#pragma unroll
    for (int bb = 0; bb < 4; ++bb)
      xv[lb][bb] = *(const f16x4*)&x_h[(size_t)(row0 + bb * 16 + lid) * 256 +
                                       wave * 64 + lb * 16 + grp * 4];

  // b/beta partial dots: vector ht reads, bank-staggered quarter
  {
    const int brow = tid & 63;
    const int q = (wave + (brow >> 3)) & 3;
    f16x8 h0 = *(const f16x8*)&ht[brow][q * 16];
    f16x8 h1 = *(const f16x8*)&ht[brow][q * 16 + 8];
    float sb = 0.f, sbt = 0.f;
#pragma unroll
    for (int j = 0; j < 8; ++j) {
      const int c = q * 16 + j;
      if (c < HDIM) {
        float hv = (float)h0[j];
        sb  += hv * Wb_all[node * HDIM + c];
        sbt += hv * Wbeta_all[node * HDIM + c];
      }
    }
#pragma unroll
    for (int j = 0; j < 8; ++j) {
      const int c = q * 16 + 8 + j;
      if (c < HDIM) {
        float hv = (float)h1[j];
        sb  += hv * Wb_all[node * HDIM + c];
        sbt += hv * Wbeta_all[node * HDIM + c];
      }
    }
    red2[wave][brow][0] = sb;
    red2[wave][brow][1] = sbt;
  }

  // ---- GEMM2 (transposed out): logits^T = Ww^T x h^T, K=64 ----
  f32x4 acc2t[4][4] = {};  // [lb][bb]: logit = wave*64+lb*16+grp*4+r, batch = bb*16+lid
#pragma unroll
  for (int kk = 0; kk < 2; ++kk) {
    f16x8 afh[4];
#pragma unroll
    for (int bb = 0; bb < 4; ++bb)
      afh[bb] = *(const f16x8*)&ht[bb * 16 + lid][kk * 32 + grp * 8];
#pragma unroll
    for (int lb = 0; lb < 4; ++lb)
#pragma unroll
      for (int bb = 0; bb < 4; ++bb)
        acc2t[lb][bb] = mfma16(bwf[kk][lb], afh[bb], acc2t[lb][bb]);
  }
  __syncthreads();   // red2 complete
  if (tid < 64) {
    bbuf[tid]    = red2[0][tid][0] + red2[1][tid][0] + red2[2][tid][0] + red2[3][tid][0]
                   + bb_all[node];
    betabuf[tid] = red2[0][tid][1] + red2[1][tid][1] + red2[2][tid][1] + red2[3][tid][1]
                   + bbeta_all[node];
  }

  // exp (no max-subtract; logits O(+-5)), sum + x-dot
  float s[4] = {0.f, 0.f, 0.f, 0.f}, dt[4] = {0.f, 0.f, 0.f, 0.f};
#pragma unroll
  for (int lb = 0; lb < 4; ++lb) {
    float4 bwv = *(const float4*)&bw_all[node * 256 + wave * 64 + lb * 16 + grp * 4];
    float bwa[4] = {bwv.x, bwv.y, bwv.z, bwv.w};
#pragma unroll
    for (int bb = 0; bb < 4; ++bb)
#pragma unroll
      for (int r = 0; r < 4; ++r) {
        float e = __expf(acc2t[lb][bb][r] + bwa[r]);
        s[bb] += e;
        dt[bb] += e * (float)xv[lb][bb][r];
      }
  }
#pragma unroll
  for (int bb = 0; bb < 4; ++bb) {
    s[bb]  += __shfl_xor(s[bb], 16, 64);  s[bb]  += __shfl_xor(s[bb], 32, 64);
    dt[bb] += __shfl_xor(dt[bb], 16, 64); dt[bb] += __shfl_xor(dt[bb], 32, 64);
  }
  if (lane < 16)
#pragma unroll
    for (int bb = 0; bb < 4; ++bb) {
      red[wave][bb * 16 + lane][0] = s[bb];
      red[wave][bb * 16 + lane][1] = dt[bb];
    }
  __syncthreads();
  if (tid < 64) {
    float S  = red[0][tid][0] + red[1][tid][0] + red[2][tid][0] + red[3][tid][0];
    float DT = red[0][tid][1] + red[1][tid][1] + red[2][tid][1] + red[3][tid][1];
    float z = betabuf[tid] * (DT / S + bbuf[tid]);
    pR[(size_t)(row0 + tid) * 32 + node] = 1.f / (1.f + __expf(-z));
  }
}

// ---------------- leaf: 8-wave (2x4), 128 rows x 256 cols ----------------
// global_load_lds staging into linear LDS [rows][64] with XOR slot swizzle
// (pre-swizzled global source + swizzled ds_read); transposed epilogue.
__global__ __launch_bounds__(512) void k_leaf(const f16* __restrict__ emb,
    const f16* __restrict__ W1T_all, const float* __restrict__ b1_all,
    const float* __restrict__ W2_all, const float* __restrict__ b2_all,
    float* __restrict__ y_leaf) {
  __shared__ f16 Alds[128 * 64];   // linear [128][64]
  __shared__ f16 Blds[256 * 64];   // linear [256][64]
  __shared__ float red[4][128];
  const int tid = threadIdx.x;
  const int wave = tid >> 6, lane = tid & 63;
  const int wm = wave >> 2, wn = wave & 3;
  const int grp = lane >> 4, lid = lane & 15;
  const int row0 = blockIdx.x * 128;
  const int leaf = blockIdx.y;
  const f16* WT = W1T_all + (size_t)leaf * 65536;
  const float* b1 = b1_all + leaf * 256;
  const float* W2 = W2_all + leaf * 256;

  const int lrow = lane >> 3;              // 0..7
  const int sslot = (lane & 7) ^ lrow;     // pre-swizzled source slot

  f32x4 acc[4][4] = {};                    // [cb][rb]: col x row (transposed)
  const int swzA = (lid & 7);              // row&7 for all frag rows
  for (int kt = 0; kt < 4; ++kt) {
    // stage A: 2 rounds x (512 lanes x 16B) = 16KB
#pragma unroll
    for (int r2 = 0; r2 < 2; ++r2) {
      const int arow = r2 * 64 + wave * 8 + lrow;
      gload16(emb + (size_t)(row0 + arow) * 256 + kt * 64 + sslot * 8,
              (char*)Alds + r2 * 8192 + wave * 1024);
    }
    // stage B: 4 rounds = 32KB
#pragma unroll
    for (int r4 = 0; r4 < 4; ++r4) {
      const int brow = r4 * 64 + wave * 8 + lrow;
      gload16(WT + (size_t)brow * 256 + kt * 64 + sslot * 8,
              (char*)Blds + r4 * 8192 + wave * 1024);
    }
    __syncthreads();   // vmcnt(0) drained by compiler before barrier
#pragma unroll
    for (int kk = 0; kk < 2; ++kk) {
      f16x8 af[4], bf[4];
#pragma unroll
      for (int rb = 0; rb < 4; ++rb) {
        const int row = wm * 64 + rb * 16 + lid;
        af[rb] = *(const f16x8*)((const char*)Alds + row * 128 +
                                 (((kk * 4 + grp) ^ swzA) << 4));
      }
#pragma unroll
      for (int cb = 0; cb < 4; ++cb) {
        const int row = wn * 64 + cb * 16 + lid;
        bf[cb] = *(const f16x8*)((const char*)Blds + row * 128 +
                                 (((kk * 4 + grp) ^ swzA) << 4));
      }
#pragma unroll
      for (int cb = 0; cb < 4; ++cb)
#pragma unroll
        for (int rb = 0; rb < 4; ++rb)
          acc[cb][rb] = mfma16(bf[cb], af[rb], acc[cb][rb]);  // col x row
    }
    __syncthreads();
  }
  // epilogue: lane holds cols {wn*64+cb*16+grp*4+r} for rows {wm*64+rb*16+lid}
  float b1a[4][4], w2a[4][4];
#pragma unroll
  for (int cb = 0; cb < 4; ++cb) {
    float4 t1 = *(const float4*)&b1[wn * 64 + cb * 16 + grp * 4];
    float4 t2 = *(const float4*)&W2[wn * 64 + cb * 16 + grp * 4];
    b1a[cb][0] = t1.x; b1a[cb][1] = t1.y; b1a[cb][2] = t1.z; b1a[cb][3] = t1.w;
    w2a[cb][0] = t2.x; w2a[cb][1] = t2.y; w2a[cb][2] = t2.z; w2a[cb][3] = t2.w;
  }
  float rs[4] = {0.f, 0.f, 0.f, 0.f};
#pragma unroll
  for (int cb = 0; cb < 4; ++cb)
#pragma unroll
    for (int rb = 0; rb < 4; ++rb)
#pragma unroll
      for (int r = 0; r < 4; ++r) {
        float v = acc[cb][rb][r] + b1a[cb][r];
        v = v > 0.f ? v : 0.f;
        rs[rb] += v * w2a[cb][r];
      }
#pragma unroll
  for (int rb = 0; rb < 4; ++rb) {
    rs[rb] += __shfl_xor(rs[rb], 16, 64);
    rs[rb] += __shfl_xor(rs[rb], 32, 64);
  }
  if (lane < 16)
#pragma unroll
    for (int rb = 0; rb < 4; ++rb)
      red[wn][wm * 64 + rb * 16 + lane] = rs[rb];
  __syncthreads();
  if (tid < 128) {
    float y = red[0][tid] + red[1][tid] + red[2][tid] + red[3][tid] + b2_all[leaf];
    y_leaf[(size_t)(row0 + tid) * 32 + leaf] = y;
  }
}

// ---------------- combine ----------------
__global__ void k_combine(const float* __restrict__ pR, const float* __restrict__ y_leaf,
                          float* __restrict__ out) {
  const int b = blockIdx.x * 256 + threadIdx.x;
  float p[32], y[32];
  const float4* pp = (const float4*)(pR + (size_t)b * 32);
  const float4* yp = (const float4*)(y_leaf + (size_t)b * 32);
#pragma unroll
  for (int i = 0; i < 8; ++i) {
    float4 v = pp[i]; p[i*4] = v.x; p[i*4+1] = v.y; p[i*4+2] = v.z; p[i*4+3] = v.w;
    float4 w = yp[i]; y[i*4] = w.x; y[i*4+1] = w.y; y[i*4+2] = w.z; y[i*4+3] = w.w;
  }
  float o = 0.f;
#pragma unroll
  for (int l = 0; l < 32; ++l) {
    float pr = 1.f;
    int node = 0;
#pragma unroll
    for (int k = 0; k < 5; ++k) {
      const int bit = (l >> (4 - k)) & 1;
      const float pv = p[node];
      pr *= bit ? pv : (1.f - pv);
      node = 2 * node + 1 + bit;
    }
    o += pr * y[l];
  }
  out[b] = o;
}

extern "C" void kernel_launch(void* const* d_in, const int* in_sizes, int n_in,
                              void* d_out, int out_size, void* d_ws, size_t ws_size,
                              hipStream_t stream) {
  (void)in_sizes; (void)n_in; (void)out_size; (void)ws_size;
  const float* x        = (const float*)d_in[0];
  const float* enc_W    = (const float*)d_in[1];
  const float* enc_b    = (const float*)d_in[2];
  const float* in_W1    = (const float*)d_in[3];
  const float* in_b1    = (const float*)d_in[4];
  const float* in_Ww    = (const float*)d_in[5];
  const float* in_bw    = (const float*)d_in[6];
  const float* in_Wb    = (const float*)d_in[7];
  const float* in_bb    = (const float*)d_in[8];
  const float* in_Wbeta = (const float*)d_in[9];
  const float* in_bbeta = (const float*)d_in[10];
  const float* lf_W1    = (const float*)d_in[11];
  const float* lf_b1    = (const float*)d_in[12];
  const float* lf_W2    = (const float*)d_in[13];
  const float* lf_b2    = (const float*)d_in[14];
  float* out = (float*)d_out;

  char* ws = (char*)d_ws;
  f16* x_h     = (f16*)(ws);                 // 4 MB
  f16* emb     = (f16*)(ws + 4194304);       // 4 MB
  f16* encWT   = (f16*)(ws + 8388608);       // 512 KB
  f16* lfW1T   = (f16*)(ws + 8912896);       // 4 MB
  f16* inW1T   = (f16*)(ws + 13107200);
  f16* inWwT   = (f16*)(ws + 14123008);
  float* pR    = (float*)(ws + 15138816);
  float* y_leaf= (float*)(ws + 16187392);

  dim3 tb(32, 8);
  hipLaunchKernelGGL(k_cast_f16, dim3(2048), dim3(256), 0, stream, x, x_h, B_ROWS * 256 / 4);
  hipLaunchKernelGGL(k_tcast, dim3(8, 8, 4),  tb, 0, stream, enc_W, encWT, 256, 256, 256, 256);
  hipLaunchKernelGGL(k_tcast, dim3(8, 8, 32), tb, 0, stream, lf_W1, lfW1T, 256, 256, 256, 256);
  hipLaunchKernelGGL(k_tcast, dim3(8, 2, 31), tb, 0, stream, in_W1, inW1T, 256, 50, 256, 64);
  hipLaunchKernelGGL(k_tcast, dim3(2, 8, 31), tb, 0, stream, in_Ww, inWwT, 50, 256, 64, 256);

  hipLaunchKernelGGL(k_enc4, dim3(256), dim3(256), 0, stream, x, encWT, enc_b, emb);
  hipLaunchKernelGGL(k_inner, dim3(128, 31), dim3(256), 0, stream, emb, inW1T, in_b1,
                     inWwT, x_h, in_bw, in_Wb, in_bb, in_Wbeta, in_bbeta, pR);
  hipLaunchKernelGGL(k_leaf, dim3(64, 32), dim3(512), 0, stream, emb, lfW1T, lf_b1, lf_W2, lf_b2, y_leaf);
  hipLaunchKernelGGL(k_combine, dim3(32), dim3(256), 0, stream, pR, y_leaf, out);
}

// Round 6
// 232.308 us; speedup vs baseline: 1.6225x; 1.0854x over previous
//
#include <hip/hip_runtime.h>

// TreeModel: soft decision tree forward. B=8192, D=E=256, H=50 (pad 64),
// 31 inner nodes, 32 leaves. MFMA fp16 16x16x32, fp32 accum/epilogues.

#define B_ROWS 8192
#define HDIM 50
#define HPAD 64

typedef _Float16 f16;
typedef _Float16 f16x8 __attribute__((ext_vector_type(8)));
typedef _Float16 f16x4 __attribute__((ext_vector_type(4)));
typedef float f32x4 __attribute__((ext_vector_type(4)));

static __device__ __forceinline__ f32x4 mfma16(f16x8 a, f16x8 b, f32x4 c) {
  // D[i][j] += sum_k a_frag[i][k] * b_frag[j][k]; i = grp*4+reg, j = lid.
  // a-frag: lane holds A[row=lid][k=grp*8..]; b-frag: B[col=lid][k=grp*8..].
  return __builtin_amdgcn_mfma_f32_16x16x32_f16(a, b, c, 0, 0, 0);
}

// async global->LDS, 16B per lane; lds base must be wave-uniform.
static __device__ __forceinline__ void gload16(const void* g, void* l) {
  __builtin_amdgcn_global_load_lds(
      (const __attribute__((address_space(1))) unsigned int*)g,
      (__attribute__((address_space(3))) unsigned int*)l, 16, 0, 0);
}

// ---------------- prep: fp32 -> fp16 cast (vector) ----------------
__global__ void k_cast_f16(const float* __restrict__ in, f16* __restrict__ out, int n4) {
  int i = blockIdx.x * blockDim.x + threadIdx.x;
  if (i < n4) {
    float4 v = reinterpret_cast<const float4*>(in)[i];
    f16x4 o = { (f16)v.x, (f16)v.y, (f16)v.z, (f16)v.w };
    reinterpret_cast<f16x4*>(out)[i] = o;
  }
}

// ---------------- prep: batched transpose-cast with zero pad ----------------
__global__ void k_tcast(const float* __restrict__ in, f16* __restrict__ out,
                        int R, int C, int Rp, int Cp) {
  __shared__ float t[32][33];
  const int s = blockIdx.z;
  const int r0 = blockIdx.x * 32, c0 = blockIdx.y * 32;
  const int tx = threadIdx.x, ty = threadIdx.y;
  const float* ip = in + (size_t)s * R * C;
  f16* op = out + (size_t)s * Cp * Rp;
#pragma unroll
  for (int i = 0; i < 4; ++i) {
    int r = r0 + ty + 8 * i, c = c0 + tx;
    t[ty + 8 * i][tx] = (r < R && c < C) ? ip[(size_t)r * C + c] : 0.f;
  }
  __syncthreads();
#pragma unroll
  for (int i = 0; i < 4; ++i) {
    int c = c0 + ty + 8 * i, r = r0 + tx;
    if (c < Cp && r < Rp) op[(size_t)c * Rp + r] = (f16)t[tx][ty + 8 * i];
  }
}

// ---------------- fused 4-layer encoder (unchanged) ----------------
__global__ __launch_bounds__(256) void k_enc4(const float* __restrict__ x,
    const f16* __restrict__ encWT, const float* __restrict__ enc_b,
    f16* __restrict__ emb) {
  __shared__ f16 act[2][32][264];
  __shared__ f16 Bt[256][72];
  const int tid = threadIdx.x;
  const int wave = tid >> 6, lane = tid & 63;
  const int grp = lane >> 4, lid = lane & 15;
  const int row0 = blockIdx.x * 32;
  const int sr = tid >> 3, sc = (tid & 7) * 8;

  {
    const int xr = tid >> 3, xc = (tid & 7) * 32;
    const float* src = x + (size_t)(row0 + xr) * 256 + xc;
#pragma unroll
    for (int j = 0; j < 4; ++j) {
      float4 a = ((const float4*)src)[2 * j];
      float4 b = ((const float4*)src)[2 * j + 1];
      f16x8 o = { (f16)a.x, (f16)a.y, (f16)a.z, (f16)a.w,
                  (f16)b.x, (f16)b.y, (f16)b.z, (f16)b.w };
      *(f16x8*)&act[0][xr][xc + 8 * j] = o;
    }
  }
  __syncthreads();

  for (int l = 0; l < 4; ++l) {
    const int cur = l & 1, nxt = cur ^ 1;
    f32x4 acc[2][4] = {};
    for (int kt = 0; kt < 4; ++kt) {
#pragma unroll
      for (int p = 0; p < 8; ++p)
        *(f16x8*)&Bt[p * 32 + sr][sc] =
            *(const f16x8*)&encWT[(size_t)l * 65536 + (size_t)(p * 32 + sr) * 256 + kt * 64 + sc];
      __syncthreads();
#pragma unroll
      for (int kk = 0; kk < 2; ++kk) {
        f16x8 af[2], bf[4];
#pragma unroll
        for (int m = 0; m < 2; ++m)
          af[m] = *(const f16x8*)&act[cur][m * 16 + lid][kt * 64 + kk * 32 + grp * 8];
#pragma unroll
        for (int n = 0; n < 4; ++n)
          bf[n] = *(const f16x8*)&Bt[wave * 64 + n * 16 + lid][kk * 32 + grp * 8];
#pragma unroll
        for (int m = 0; m < 2; ++m)
#pragma unroll
          for (int n = 0; n < 4; ++n) acc[m][n] = mfma16(af[m], bf[n], acc[m][n]);
      }
      __syncthreads();
    }
#pragma unroll
    for (int n = 0; n < 4; ++n) {
      const int col = wave * 64 + n * 16 + lid;
      const float bv = enc_b[l * 256 + col];
#pragma unroll
      for (int m = 0; m < 2; ++m)
#pragma unroll
        for (int r = 0; r < 4; ++r) {
          float v = acc[m][n][r] + bv;
          act[nxt][m * 16 + grp * 4 + r][col] = (f16)(v > 0.f ? v : 0.f);
        }
    }
    __syncthreads();
  }
  {
    const int xr = tid >> 3, xc = (tid & 7) * 32;
#pragma unroll
    for (int j = 0; j < 4; ++j)
      *(f16x8*)&emb[(size_t)(row0 + xr) * 256 + xc + 8 * j] =
          *(const f16x8*)&act[0][xr][xc + 8 * j];
  }
}

// ---------------- fused inner nodes: wave-private node design ----------------
// Block = 64 rows x 4 nodes, 4 waves; wave w owns node (by*4+w) end-to-end.
// One barrier pair (emb stage); all else wave-local (LDS producer=consumer).
// GEMM1: D1T[hdim][batch] = mfma(W1frag, embfrag); h -> wave-private LDS
// (batch-major). GEMM2 in 4 x 64-logit chunks, transposed out, softmax fused.
__global__ __launch_bounds__(256, 2) void k_inner(const f16* __restrict__ emb,
    const f16* __restrict__ W1T_all, const float* __restrict__ b1_all,
    const f16* __restrict__ WwT_all, const f16* __restrict__ x_h,
    const float* __restrict__ bw_all, const float* __restrict__ Wb_all,
    const float* __restrict__ bb_all, const float* __restrict__ Wbeta_all,
    const float* __restrict__ bbeta_all, float* __restrict__ pR) {
  __shared__ f16 et[64][264];            // emb tile (shared, staged once)
  __shared__ f16 hbuf[4][64][72];        // wave-private h (batch-major)
  __shared__ float bbuf[4][64], betabuf[4][64];

  const int tid = threadIdx.x;
  const int wave = tid >> 6, lane = tid & 63;
  const int grp = lane >> 4, lid = lane & 15;
  const int row0 = blockIdx.x * 64;
  const int node = blockIdx.y * 4 + wave;

  // cooperative emb stage: 256 threads x 64 f16 each
  {
    const int r = tid >> 2, cb = (tid & 3) * 64;
#pragma unroll
    for (int j = 0; j < 8; ++j)
      *(f16x8*)&et[r][cb + 8 * j] =
          *(const f16x8*)&emb[(size_t)(row0 + r) * 256 + cb + 8 * j];
  }
  __syncthreads();
  if (node >= 31) return;

  const f16* W1T = W1T_all + (size_t)node * HPAD * 256;   // [64][256]
  const f16* WwT = WwT_all + (size_t)node * 256 * HPAD;   // [256][64]

  // ---- GEMM1: h^T = W1^T emb^T, 64 hdim x 64 batch, K=256 (8 ksteps) ----
  f32x4 acc1[4][4] = {};   // [h4][m]
  f16x8 wf[2][4];
#pragma unroll
  for (int h4 = 0; h4 < 4; ++h4)
    wf[0][h4] = *(const f16x8*)&W1T[(size_t)(h4 * 16 + lid) * 256 + grp * 8];
  for (int kt = 0; kt < 8; ++kt) {
    const int cur = kt & 1, nxt = cur ^ 1;
    if (kt < 7) {
#pragma unroll
      for (int h4 = 0; h4 < 4; ++h4)
        wf[nxt][h4] = *(const f16x8*)&W1T[(size_t)(h4 * 16 + lid) * 256 +
                                          (kt + 1) * 32 + grp * 8];
    }
    f16x8 af[4];
#pragma unroll
    for (int m = 0; m < 4; ++m)
      af[m] = *(const f16x8*)&et[m * 16 + lid][kt * 32 + grp * 8];
#pragma unroll
    for (int h4 = 0; h4 < 4; ++h4)
#pragma unroll
      for (int m = 0; m < 4; ++m)
        acc1[h4][m] = mfma16(wf[cur][h4], af[m], acc1[h4][m]);
  }
  // h epilogue -> wave-private LDS, batch-major [64][72]
#pragma unroll
  for (int h4 = 0; h4 < 4; ++h4) {
    const int hc = h4 * 16 + grp * 4;
    float bva[4];
#pragma unroll
    for (int r = 0; r < 4; ++r)
      bva[r] = (hc + r < HDIM) ? b1_all[node * HDIM + hc + r] : 0.f;
#pragma unroll
    for (int m = 0; m < 4; ++m) {
      f16x4 hv;
#pragma unroll
      for (int r = 0; r < 4; ++r) {
        float v = acc1[h4][m][r] + bva[r];
        hv[r] = (f16)(v > 0.f ? v : 0.f);
      }
      *(f16x4*)&hbuf[wave][m * 16 + lid][hc] = hv;
    }
  }

  // b/beta dots: one batch row per lane (h cols >= 50 are exactly 0)
  {
    float sb = 0.f, sbt = 0.f;
#pragma unroll
    for (int v8 = 0; v8 < 7; ++v8) {
      f16x8 hv = *(const f16x8*)&hbuf[wave][lane][v8 * 8];
#pragma unroll
      for (int j = 0; j < 8; ++j) {
        const int c = v8 * 8 + j;
        if (c < HDIM) {
          float hvf = (float)hv[j];
          sb  += hvf * Wb_all[node * HDIM + c];
          sbt += hvf * Wbeta_all[node * HDIM + c];
        }
      }
    }
    bbuf[wave][lane] = sb + bb_all[node];
    betabuf[wave][lane] = sbt + bbeta_all[node];
  }

  // ---- GEMM2 + fused softmax: 4 chunks of 64 logits ----
  float s[4] = {0.f, 0.f, 0.f, 0.f}, dt[4] = {0.f, 0.f, 0.f, 0.f};
  for (int c = 0; c < 4; ++c) {
    f16x8 awf[2][4];
#pragma unroll
    for (int kk = 0; kk < 2; ++kk)
#pragma unroll
      for (int n4 = 0; n4 < 4; ++n4)
        awf[kk][n4] = *(const f16x8*)&WwT[(size_t)(c * 64 + n4 * 16 + lid) * HPAD +
                                          kk * 32 + grp * 8];
    f32x4 acc2[4][4] = {};   // [n4][m]: logit = c*64+n4*16+grp*4+r, batch = m*16+lid
#pragma unroll
    for (int kk = 0; kk < 2; ++kk) {
      f16x8 hf[4];
#pragma unroll
      for (int m = 0; m < 4; ++m)
        hf[m] = *(const f16x8*)&hbuf[wave][m * 16 + lid][kk * 32 + grp * 8];
#pragma unroll
      for (int n4 = 0; n4 < 4; ++n4)
#pragma unroll
        for (int m = 0; m < 4; ++m)
          acc2[n4][m] = mfma16(awf[kk][n4], hf[m], acc2[n4][m]);
    }
    // fused epilogue: exp (no max-subtract; logits O(+-5)), sum + x-dot
#pragma unroll
    for (int n4 = 0; n4 < 4; ++n4) {
      float4 bwv = *(const float4*)&bw_all[node * 256 + c * 64 + n4 * 16 + grp * 4];
      float bwa[4] = {bwv.x, bwv.y, bwv.z, bwv.w};
#pragma unroll
      for (int m = 0; m < 4; ++m) {
        f16x4 xv = *(const f16x4*)&x_h[(size_t)(row0 + m * 16 + lid) * 256 +
                                       c * 64 + n4 * 16 + grp * 4];
#pragma unroll
        for (int r = 0; r < 4; ++r) {
          float e = __expf(acc2[n4][m][r] + bwa[r]);
          s[m] += e;
          dt[m] += e * (float)xv[r];
        }
      }
    }
  }
  // reduce over grp (xor 16 + 32 covers all 4 k-groups)
#pragma unroll
  for (int m = 0; m < 4; ++m) {
    s[m]  += __shfl_xor(s[m], 16, 64);  s[m]  += __shfl_xor(s[m], 32, 64);
    dt[m] += __shfl_xor(dt[m], 16, 64); dt[m] += __shfl_xor(dt[m], 32, 64);
  }
  if (grp == 0) {
#pragma unroll
    for (int m = 0; m < 4; ++m) {
      const int row = m * 16 + lid;
      float z = betabuf[wave][row] * (dt[m] / s[m] + bbuf[wave][row]);
      pR[(size_t)(row0 + row) * 32 + node] = 1.f / (1.f + __expf(-z));
    }
  }
}

// ---------------- leaf: 8-wave (2x4), 128 rows x 256 cols (unchanged) ------
__global__ __launch_bounds__(512) void k_leaf(const f16* __restrict__ emb,
    const f16* __restrict__ W1T_all, const float* __restrict__ b1_all,
    const float* __restrict__ W2_all, const float* __restrict__ b2_all,
    float* __restrict__ y_leaf) {
  __shared__ f16 Alds[128 * 64];   // linear [128][64]
  __shared__ f16 Blds[256 * 64];   // linear [256][64]
  __shared__ float red[4][128];
  const int tid = threadIdx.x;
  const int wave = tid >> 6, lane = tid & 63;
  const int wm = wave >> 2, wn = wave & 3;
  const int grp = lane >> 4, lid = lane & 15;
  const int row0 = blockIdx.x * 128;
  const int leaf = blockIdx.y;
  const f16* WT = W1T_all + (size_t)leaf * 65536;
  const float* b1 = b1_all + leaf * 256;
  const float* W2 = W2_all + leaf * 256;

  const int lrow = lane >> 3;              // 0..7
  const int sslot = (lane & 7) ^ lrow;     // pre-swizzled source slot

  f32x4 acc[4][4] = {};                    // [cb][rb]: col x row (transposed)
  const int swzA = (lid & 7);              // row&7 for all frag rows
  for (int kt = 0; kt < 4; ++kt) {
#pragma unroll
    for (int r2 = 0; r2 < 2; ++r2) {
      const int arow = r2 * 64 + wave * 8 + lrow;
      gload16(emb + (size_t)(row0 + arow) * 256 + kt * 64 + sslot * 8,
              (char*)Alds + r2 * 8192 + wave * 1024);
    }
#pragma unroll
    for (int r4 = 0; r4 < 4; ++r4) {
      const int brow = r4 * 64 + wave * 8 + lrow;
      gload16(WT + (size_t)brow * 256 + kt * 64 + sslot * 8,
              (char*)Blds + r4 * 8192 + wave * 1024);
    }
    __syncthreads();
#pragma unroll
    for (int kk = 0; kk < 2; ++kk) {
      f16x8 af[4], bf[4];
#pragma unroll
      for (int rb = 0; rb < 4; ++rb) {
        const int row = wm * 64 + rb * 16 + lid;
        af[rb] = *(const f16x8*)((const char*)Alds + row * 128 +
                                 (((kk * 4 + grp) ^ swzA) << 4));
      }
#pragma unroll
      for (int cb = 0; cb < 4; ++cb) {
        const int row = wn * 64 + cb * 16 + lid;
        bf[cb] = *(const f16x8*)((const char*)Blds + row * 128 +
                                 (((kk * 4 + grp) ^ swzA) << 4));
      }
#pragma unroll
      for (int cb = 0; cb < 4; ++cb)
#pragma unroll
        for (int rb = 0; rb < 4; ++rb)
          acc[cb][rb] = mfma16(bf[cb], af[rb], acc[cb][rb]);  // col x row
    }
    __syncthreads();
  }
  float b1a[4][4], w2a[4][4];
#pragma unroll
  for (int cb = 0; cb < 4; ++cb) {
    float4 t1 = *(const float4*)&b1[wn * 64 + cb * 16 + grp * 4];
    float4 t2 = *(const float4*)&W2[wn * 64 + cb * 16 + grp * 4];
    b1a[cb][0] = t1.x; b1a[cb][1] = t1.y; b1a[cb][2] = t1.z; b1a[cb][3] = t1.w;
    w2a[cb][0] = t2.x; w2a[cb][1] = t2.y; w2a[cb][2] = t2.z; w2a[cb][3] = t2.w;
  }
  float rs[4] = {0.f, 0.f, 0.f, 0.f};
#pragma unroll
  for (int cb = 0; cb < 4; ++cb)
#pragma unroll
    for (int rb = 0; rb < 4; ++rb)
#pragma unroll
      for (int r = 0; r < 4; ++r) {
        float v = acc[cb][rb][r] + b1a[cb][r];
        v = v > 0.f ? v : 0.f;
        rs[rb] += v * w2a[cb][r];
      }
#pragma unroll
  for (int rb = 0; rb < 4; ++rb) {
    rs[rb] += __shfl_xor(rs[rb], 16, 64);
    rs[rb] += __shfl_xor(rs[rb], 32, 64);
  }
  if (lane < 16)
#pragma unroll
    for (int rb = 0; rb < 4; ++rb)
      red[wn][wm * 64 + rb * 16 + lane] = rs[rb];
  __syncthreads();
  if (tid < 128) {
    float y = red[0][tid] + red[1][tid] + red[2][tid] + red[3][tid] + b2_all[leaf];
    y_leaf[(size_t)(row0 + tid) * 32 + leaf] = y;
  }
}

// ---------------- combine ----------------
__global__ void k_combine(const float* __restrict__ pR, const float* __restrict__ y_leaf,
                          float* __restrict__ out) {
  const int b = blockIdx.x * 256 + threadIdx.x;
  float p[32], y[32];
  const float4* pp = (const float4*)(pR + (size_t)b * 32);
  const float4* yp = (const float4*)(y_leaf + (size_t)b * 32);
#pragma unroll
  for (int i = 0; i < 8; ++i) {
    float4 v = pp[i]; p[i*4] = v.x; p[i*4+1] = v.y; p[i*4+2] = v.z; p[i*4+3] = v.w;
    float4 w = yp[i]; y[i*4] = w.x; y[i*4+1] = w.y; y[i*4+2] = w.z; y[i*4+3] = w.w;
  }
  float o = 0.f;
#pragma unroll
  for (int l = 0; l < 32; ++l) {
    float pr = 1.f;
    int node = 0;
#pragma unroll
    for (int k = 0; k < 5; ++k) {
      const int bit = (l >> (4 - k)) & 1;
      const float pv = p[node];
      pr *= bit ? pv : (1.f - pv);
      node = 2 * node + 1 + bit;
    }
    o += pr * y[l];
  }
  out[b] = o;
}

extern "C" void kernel_launch(void* const* d_in, const int* in_sizes, int n_in,
                              void* d_out, int out_size, void* d_ws, size_t ws_size,
                              hipStream_t stream) {
  (void)in_sizes; (void)n_in; (void)out_size; (void)ws_size;
  const float* x        = (const float*)d_in[0];
  const float* enc_W    = (const float*)d_in[1];
  const float* enc_b    = (const float*)d_in[2];
  const float* in_W1    = (const float*)d_in[3];
  const float* in_b1    = (const float*)d_in[4];
  const float* in_Ww    = (const float*)d_in[5];
  const float* in_bw    = (const float*)d_in[6];
  const float* in_Wb    = (const float*)d_in[7];
  const float* in_bb    = (const float*)d_in[8];
  const float* in_Wbeta = (const float*)d_in[9];
  const float* in_bbeta = (const float*)d_in[10];
  const float* lf_W1    = (const float*)d_in[11];
  const float* lf_b1    = (const float*)d_in[12];
  const float* lf_W2    = (const float*)d_in[13];
  const float* lf_b2    = (const float*)d_in[14];
  float* out = (float*)d_out;

  char* ws = (char*)d_ws;
  f16* x_h     = (f16*)(ws);                 // 4 MB
  f16* emb     = (f16*)(ws + 4194304);       // 4 MB
  f16* encWT   = (f16*)(ws + 8388608);       // 512 KB
  f16* lfW1T   = (f16*)(ws + 8912896);       // 4 MB
  f16* inW1T   = (f16*)(ws + 13107200);
  f16* inWwT   = (f16*)(ws + 14123008);
  float* pR    = (float*)(ws + 15138816);
  float* y_leaf= (float*)(ws + 16187392);

  dim3 tb(32, 8);
  hipLaunchKernelGGL(k_cast_f16, dim3(2048), dim3(256), 0, stream, x, x_h, B_ROWS * 256 / 4);
  hipLaunchKernelGGL(k_tcast, dim3(8, 8, 4),  tb, 0, stream, enc_W, encWT, 256, 256, 256, 256);
  hipLaunchKernelGGL(k_tcast, dim3(8, 8, 32), tb, 0, stream, lf_W1, lfW1T, 256, 256, 256, 256);
  hipLaunchKernelGGL(k_tcast, dim3(8, 2, 31), tb, 0, stream, in_W1, inW1T, 256, 50, 256, 64);
  hipLaunchKernelGGL(k_tcast, dim3(2, 8, 31), tb, 0, stream, in_Ww, inWwT, 50, 256, 64, 256);

  hipLaunchKernelGGL(k_enc4, dim3(256), dim3(256), 0, stream, x, encWT, enc_b, emb);
  hipLaunchKernelGGL(k_inner, dim3(128, 8), dim3(256), 0, stream, emb, inW1T, in_b1,
                     inWwT, x_h, in_bw, in_Wb, in_bb, in_Wbeta, in_bbeta, pR);
  hipLaunchKernelGGL(k_leaf, dim3(64, 32), dim3(512), 0, stream, emb, lfW1T, lf_b1, lf_W2, lf_b2, y_leaf);
  hipLaunchKernelGGL(k_combine, dim3(32), dim3(256), 0, stream, pR, y_leaf, out);
}

// Round 7
// 214.887 us; speedup vs baseline: 1.7541x; 1.0811x over previous
//
#include <hip/hip_runtime.h>

// TreeModel: soft decision tree forward. B=8192, D=E=256, H=50 (pad 64),
// 31 inner nodes, 32 leaves. MFMA fp16 16x16x32, fp32 accum/epilogues.

#define B_ROWS 8192
#define HDIM 50
#define HPAD 64

typedef _Float16 f16;
typedef _Float16 f16x8 __attribute__((ext_vector_type(8)));
typedef _Float16 f16x4 __attribute__((ext_vector_type(4)));
typedef float f32x4 __attribute__((ext_vector_type(4)));

static __device__ __forceinline__ f32x4 mfma16(f16x8 a, f16x8 b, f32x4 c) {
  // D[i][j] += sum_k a_frag[i][k] * b_frag[j][k]; i = grp*4+reg, j = lid.
  // a-frag: lane holds A[row=lid][k=grp*8..]; b-frag: B[col=lid][k=grp*8..].
  return __builtin_amdgcn_mfma_f32_16x16x32_f16(a, b, c, 0, 0, 0);
}

// async global->LDS, 16B per lane; lds base must be wave-uniform.
static __device__ __forceinline__ void gload16(const void* g, void* l) {
  __builtin_amdgcn_global_load_lds(
      (const __attribute__((address_space(1))) unsigned int*)g,
      (__attribute__((address_space(3))) unsigned int*)l, 16, 0, 0);
}

// ---------------- prep: fp32 -> fp16 cast (vector) ----------------
__global__ void k_cast_f16(const float* __restrict__ in, f16* __restrict__ out, int n4) {
  int i = blockIdx.x * blockDim.x + threadIdx.x;
  if (i < n4) {
    float4 v = reinterpret_cast<const float4*>(in)[i];
    f16x4 o = { (f16)v.x, (f16)v.y, (f16)v.z, (f16)v.w };
    reinterpret_cast<f16x4*>(out)[i] = o;
  }
}

// ---------------- prep: batched transpose-cast with zero pad ----------------
__global__ void k_tcast(const float* __restrict__ in, f16* __restrict__ out,
                        int R, int C, int Rp, int Cp) {
  __shared__ float t[32][33];
  const int s = blockIdx.z;
  const int r0 = blockIdx.x * 32, c0 = blockIdx.y * 32;
  const int tx = threadIdx.x, ty = threadIdx.y;
  const float* ip = in + (size_t)s * R * C;
  f16* op = out + (size_t)s * Cp * Rp;
#pragma unroll
  for (int i = 0; i < 4; ++i) {
    int r = r0 + ty + 8 * i, c = c0 + tx;
    t[ty + 8 * i][tx] = (r < R && c < C) ? ip[(size_t)r * C + c] : 0.f;
  }
  __syncthreads();
#pragma unroll
  for (int i = 0; i < 4; ++i) {
    int c = c0 + ty + 8 * i, r = r0 + tx;
    if (c < Cp && r < Rp) op[(size_t)c * Rp + r] = (f16)t[tx][ty + 8 * i];
  }
}

// ---------------- prep: build WwE[272][64] per node ----------------
// rows 0..255: WwE[d][h] = Ww[node][h][d] (h<50, else 0)  [logit-major]
// row 256 = Wb[node][:], row 257 = Wbeta[node][:], rows 258..271 = 0.
__global__ void k_prep_ww(const float* __restrict__ Ww, const float* __restrict__ Wb,
                          const float* __restrict__ Wbeta, f16* __restrict__ WwE) {
  const int node = blockIdx.x;
  const int d = threadIdx.x;  // 0..255
  f16 row[64];
#pragma unroll
  for (int h = 0; h < 64; ++h)
    row[h] = (h < HDIM) ? (f16)Ww[((size_t)node * HDIM + h) * 256 + d] : (f16)0.f;
  f16* dst = WwE + (size_t)node * 272 * 64 + (size_t)d * 64;
#pragma unroll
  for (int j = 0; j < 8; ++j) *(f16x8*)&dst[j * 8] = *(const f16x8*)&row[j * 8];
  if (d < 16) {
    f16 er[64];
#pragma unroll
    for (int h = 0; h < 64; ++h) {
      float v = 0.f;
      if (d == 0 && h < HDIM) v = Wb[node * HDIM + h];
      if (d == 1 && h < HDIM) v = Wbeta[node * HDIM + h];
      er[h] = (f16)v;
    }
    f16* dst2 = WwE + (size_t)node * 272 * 64 + (size_t)(256 + d) * 64;
#pragma unroll
    for (int j = 0; j < 8; ++j) *(f16x8*)&dst2[j * 8] = *(const f16x8*)&er[j * 8];
  }
}

// ---------------- fused 4-layer encoder (unchanged) ----------------
__global__ __launch_bounds__(256) void k_enc4(const float* __restrict__ x,
    const f16* __restrict__ encWT, const float* __restrict__ enc_b,
    f16* __restrict__ emb) {
  __shared__ f16 act[2][32][264];
  __shared__ f16 Bt[256][72];
  const int tid = threadIdx.x;
  const int wave = tid >> 6, lane = tid & 63;
  const int grp = lane >> 4, lid = lane & 15;
  const int row0 = blockIdx.x * 32;
  const int sr = tid >> 3, sc = (tid & 7) * 8;

  {
    const int xr = tid >> 3, xc = (tid & 7) * 32;
    const float* src = x + (size_t)(row0 + xr) * 256 + xc;
#pragma unroll
    for (int j = 0; j < 4; ++j) {
      float4 a = ((const float4*)src)[2 * j];
      float4 b = ((const float4*)src)[2 * j + 1];
      f16x8 o = { (f16)a.x, (f16)a.y, (f16)a.z, (f16)a.w,
                  (f16)b.x, (f16)b.y, (f16)b.z, (f16)b.w };
      *(f16x8*)&act[0][xr][xc + 8 * j] = o;
    }
  }
  __syncthreads();

  for (int l = 0; l < 4; ++l) {
    const int cur = l & 1, nxt = cur ^ 1;
    f32x4 acc[2][4] = {};
    for (int kt = 0; kt < 4; ++kt) {
#pragma unroll
      for (int p = 0; p < 8; ++p)
        *(f16x8*)&Bt[p * 32 + sr][sc] =
            *(const f16x8*)&encWT[(size_t)l * 65536 + (size_t)(p * 32 + sr) * 256 + kt * 64 + sc];
      __syncthreads();
#pragma unroll
      for (int kk = 0; kk < 2; ++kk) {
        f16x8 af[2], bf[4];
#pragma unroll
        for (int m = 0; m < 2; ++m)
          af[m] = *(const f16x8*)&act[cur][m * 16 + lid][kt * 64 + kk * 32 + grp * 8];
#pragma unroll
        for (int n = 0; n < 4; ++n)
          bf[n] = *(const f16x8*)&Bt[wave * 64 + n * 16 + lid][kk * 32 + grp * 8];
#pragma unroll
        for (int m = 0; m < 2; ++m)
#pragma unroll
          for (int n = 0; n < 4; ++n) acc[m][n] = mfma16(af[m], bf[n], acc[m][n]);
      }
      __syncthreads();
    }
#pragma unroll
    for (int n = 0; n < 4; ++n) {
      const int col = wave * 64 + n * 16 + lid;
      const float bv = enc_b[l * 256 + col];
#pragma unroll
      for (int m = 0; m < 2; ++m)
#pragma unroll
        for (int r = 0; r < 4; ++r) {
          float v = acc[m][n][r] + bv;
          act[nxt][m * 16 + grp * 4 + r][col] = (f16)(v > 0.f ? v : 0.f);
        }
    }
    __syncthreads();
  }
  {
    const int xr = tid >> 3, xc = (tid & 7) * 32;
#pragma unroll
    for (int j = 0; j < 4; ++j)
      *(f16x8*)&emb[(size_t)(row0 + xr) * 256 + xc + 8 * j] =
          *(const f16x8*)&act[0][xr][xc + 8 * j];
  }
}

// ---------------- fused inner nodes: wave-private node design ----------------
// Block = 64 rows x 4 nodes, 4 waves; wave w owns node end-to-end.
// b/beta folded into WwE rows 256/257 (one mini-MFMA). x tile staged to LDS
// once per block (reuses emb-tile buffer). 3 uniform barriers per block.
__global__ __launch_bounds__(256, 2) void k_inner(const f16* __restrict__ emb,
    const f16* __restrict__ W1T_all, const float* __restrict__ b1_all,
    const f16* __restrict__ WwE_all, const f16* __restrict__ x_h,
    const float* __restrict__ bw_all, const float* __restrict__ bb_all,
    const float* __restrict__ bbeta_all, float* __restrict__ pR) {
  __shared__ f16 et[64][264];            // emb tile, then x tile (reused)
  __shared__ f16 hbuf[4][64][72];        // wave-private h (batch-major)

  const int tid = threadIdx.x;
  const int wave = tid >> 6, lane = tid & 63;
  const int grp = lane >> 4, lid = lane & 15;
  const int row0 = blockIdx.x * 64;
  const int node_raw = blockIdx.y * 4 + wave;
  const int node = node_raw < 31 ? node_raw : 30;

  // cooperative emb stage: 256 threads x 64 f16 each
  {
    const int r = tid >> 2, cb = (tid & 3) * 64;
#pragma unroll
    for (int j = 0; j < 8; ++j)
      *(f16x8*)&et[r][cb + 8 * j] =
          *(const f16x8*)&emb[(size_t)(row0 + r) * 256 + cb + 8 * j];
  }
  __syncthreads();

  const f16* W1T = W1T_all + (size_t)node * HPAD * 256;   // [64][256]
  const f16* WwE = WwE_all + (size_t)node * 272 * 64;     // [272][64]

  // ---- GEMM1: h^T = W1^T emb^T, 64 hdim x 64 batch, K=256 (8 ksteps) ----
  f32x4 acc1[4][4] = {};   // [h4][m]
  f16x8 wf[2][4];
#pragma unroll
  for (int h4 = 0; h4 < 4; ++h4)
    wf[0][h4] = *(const f16x8*)&W1T[(size_t)(h4 * 16 + lid) * 256 + grp * 8];
  for (int kt = 0; kt < 8; ++kt) {
    const int cur = kt & 1, nxt = cur ^ 1;
    if (kt < 7) {
#pragma unroll
      for (int h4 = 0; h4 < 4; ++h4)
        wf[nxt][h4] = *(const f16x8*)&W1T[(size_t)(h4 * 16 + lid) * 256 +
                                          (kt + 1) * 32 + grp * 8];
    }
    f16x8 af[4];
#pragma unroll
    for (int m = 0; m < 4; ++m)
      af[m] = *(const f16x8*)&et[m * 16 + lid][kt * 32 + grp * 8];
#pragma unroll
    for (int h4 = 0; h4 < 4; ++h4)
#pragma unroll
      for (int m = 0; m < 4; ++m)
        acc1[h4][m] = mfma16(wf[cur][h4], af[m], acc1[h4][m]);
  }
  // h epilogue -> wave-private LDS, batch-major [64][72]
#pragma unroll
  for (int h4 = 0; h4 < 4; ++h4) {
    const int hc = h4 * 16 + grp * 4;
    float bva[4];
#pragma unroll
    for (int r = 0; r < 4; ++r)
      bva[r] = (hc + r < HDIM) ? b1_all[node * HDIM + hc + r] : 0.f;
#pragma unroll
    for (int m = 0; m < 4; ++m) {
      f16x4 hv;
#pragma unroll
      for (int r = 0; r < 4; ++r) {
        float v = acc1[h4][m][r] + bva[r];
        hv[r] = (f16)(v > 0.f ? v : 0.f);
      }
      *(f16x4*)&hbuf[wave][m * 16 + lid][hc] = hv;
    }
  }
  __syncthreads();   // all waves done reading et
  // stage x tile into et region (block-shared, 4x reuse)
  {
    const int r = tid >> 2, cb = (tid & 3) * 64;
#pragma unroll
    for (int j = 0; j < 8; ++j)
      *(f16x8*)&et[r][cb + 8 * j] =
          *(const f16x8*)&x_h[(size_t)(row0 + r) * 256 + cb + 8 * j];
  }
  __syncthreads();

  // ---- mini-chunk: b/beta dots via MFMA (WwE rows 256..271) ----
  f32x4 accm[4] = {};   // [m]; grp0: reg0 = b-dot, reg1 = beta-dot
#pragma unroll
  for (int kk = 0; kk < 2; ++kk) {
    f16x8 wmini = *(const f16x8*)&WwE[(size_t)(256 + lid) * 64 + kk * 32 + grp * 8];
#pragma unroll
    for (int m = 0; m < 4; ++m) {
      f16x8 hf = *(const f16x8*)&hbuf[wave][m * 16 + lid][kk * 32 + grp * 8];
      accm[m] = mfma16(wmini, hf, accm[m]);
    }
  }

  // ---- GEMM2 + fused softmax: 4 chunks of 64 logits ----
  float s[4] = {0.f, 0.f, 0.f, 0.f}, dt[4] = {0.f, 0.f, 0.f, 0.f};
  for (int c = 0; c < 4; ++c) {
    f16x8 awf[2][4];
#pragma unroll
    for (int kk = 0; kk < 2; ++kk)
#pragma unroll
      for (int n4 = 0; n4 < 4; ++n4)
        awf[kk][n4] = *(const f16x8*)&WwE[(size_t)(c * 64 + n4 * 16 + lid) * 64 +
                                          kk * 32 + grp * 8];
    f32x4 acc2[4][4] = {};   // [n4][m]: logit = c*64+n4*16+grp*4+r, batch = m*16+lid
#pragma unroll
    for (int kk = 0; kk < 2; ++kk) {
      f16x8 hf[4];
#pragma unroll
      for (int m = 0; m < 4; ++m)
        hf[m] = *(const f16x8*)&hbuf[wave][m * 16 + lid][kk * 32 + grp * 8];
#pragma unroll
      for (int n4 = 0; n4 < 4; ++n4)
#pragma unroll
        for (int m = 0; m < 4; ++m)
          acc2[n4][m] = mfma16(awf[kk][n4], hf[m], acc2[n4][m]);
    }
    // fused epilogue: exp (no max-subtract; logits O(+-5)), sum + x-dot (x from LDS)
#pragma unroll
    for (int n4 = 0; n4 < 4; ++n4) {
      float4 bwv = *(const float4*)&bw_all[node * 256 + c * 64 + n4 * 16 + grp * 4];
      float bwa[4] = {bwv.x, bwv.y, bwv.z, bwv.w};
#pragma unroll
      for (int m = 0; m < 4; ++m) {
        f16x4 xv = *(const f16x4*)&et[m * 16 + lid][c * 64 + n4 * 16 + grp * 4];
#pragma unroll
        for (int r = 0; r < 4; ++r) {
          float e = __expf(acc2[n4][m][r] + bwa[r]);
          s[m] += e;
          dt[m] += e * (float)xv[r];
        }
      }
    }
  }
  // reduce over grp (xor 16 + 32 covers all 4 k-groups)
#pragma unroll
  for (int m = 0; m < 4; ++m) {
    s[m]  += __shfl_xor(s[m], 16, 64);  s[m]  += __shfl_xor(s[m], 32, 64);
    dt[m] += __shfl_xor(dt[m], 16, 64); dt[m] += __shfl_xor(dt[m], 32, 64);
  }
  if (grp == 0 && node_raw < 31) {
    const float bbv = bb_all[node], bbetav = bbeta_all[node];
#pragma unroll
    for (int m = 0; m < 4; ++m) {
      const int row = m * 16 + lid;
      float b = accm[m][0] + bbv;
      float beta = accm[m][1] + bbetav;
      float z = beta * (dt[m] / s[m] + b);
      pR[(size_t)(row0 + row) * 32 + node] = 1.f / (1.f + __expf(-z));
    }
  }
}

// ---------------- leaf: 8-wave (2x4), 256 rows x 256 cols, dbuf pipeline ----
// global_load_lds into double-buffered linear LDS with XOR slot swizzle;
// next-kt stage issued BEFORE current-kt compute (2-phase pipeline).
__global__ __launch_bounds__(512) void k_leaf(const f16* __restrict__ emb,
    const f16* __restrict__ W1T_all, const float* __restrict__ b1_all,
    const float* __restrict__ W2_all, const float* __restrict__ b2_all,
    float* __restrict__ y_leaf) {
  __shared__ f16 Albuf[2][256 * 64];   // [256 rows][64 k] linear, 32KB each
  __shared__ f16 Blbuf[2][256 * 64];
  __shared__ float red[4][256];
  const int tid = threadIdx.x;
  const int wave = tid >> 6, lane = tid & 63;
  const int wm = wave >> 2, wn = wave & 3;
  const int grp = lane >> 4, lid = lane & 15;
  const int row0 = blockIdx.x * 256;
  const int leaf = blockIdx.y;
  const f16* WT = W1T_all + (size_t)leaf * 65536;
  const float* b1 = b1_all + leaf * 256;
  const float* W2 = W2_all + leaf * 256;

  const int lrow = lane >> 3;              // 0..7
  const int sslot = (lane & 7) ^ lrow;     // pre-swizzled source slot
  const int swzA = (lid & 7);

#define LEAF_STAGE(buf, kt)                                                    \
  {                                                                            \
    _Pragma("unroll")                                                          \
    for (int r4 = 0; r4 < 4; ++r4) {                                           \
      const int rr = r4 * 64 + wave * 8 + lrow;                                \
      gload16(emb + (size_t)(row0 + rr) * 256 + (kt) * 64 + sslot * 8,         \
              (char*)&Albuf[buf][0] + r4 * 8192 + wave * 1024);                \
      gload16(WT + (size_t)rr * 256 + (kt) * 64 + sslot * 8,                   \
              (char*)&Blbuf[buf][0] + r4 * 8192 + wave * 1024);                \
    }                                                                          \
  }

  f32x4 acc[4][8] = {};                    // [cb][rb]: col x row (transposed)
  LEAF_STAGE(0, 0);
  __syncthreads();
  for (int kt = 0; kt < 4; ++kt) {
    const int b = kt & 1;
    if (kt < 3) LEAF_STAGE(b ^ 1, kt + 1);
#pragma unroll
    for (int kk = 0; kk < 2; ++kk) {
      f16x8 af[8], bf[4];
#pragma unroll
      for (int rb = 0; rb < 8; ++rb) {
        const int row = wm * 128 + rb * 16 + lid;
        af[rb] = *(const f16x8*)((const char*)&Albuf[b][0] + row * 128 +
                                 (((kk * 4 + grp) ^ swzA) << 4));
      }
#pragma unroll
      for (int cb = 0; cb < 4; ++cb) {
        const int col = wn * 64 + cb * 16 + lid;
        bf[cb] = *(const f16x8*)((const char*)&Blbuf[b][0] + col * 128 +
                                 (((kk * 4 + grp) ^ swzA) << 4));
      }
#pragma unroll
      for (int cb = 0; cb < 4; ++cb)
#pragma unroll
        for (int rb = 0; rb < 8; ++rb)
          acc[cb][rb] = mfma16(bf[cb], af[rb], acc[cb][rb]);  // col x row
    }
    if (kt < 3) __syncthreads();
  }
  // epilogue: lane holds cols {wn*64+cb*16+grp*4+r} for rows {wm*128+rb*16+lid}
  float b1a[4][4], w2a[4][4];
#pragma unroll
  for (int cb = 0; cb < 4; ++cb) {
    float4 t1 = *(const float4*)&b1[wn * 64 + cb * 16 + grp * 4];
    float4 t2 = *(const float4*)&W2[wn * 64 + cb * 16 + grp * 4];
    b1a[cb][0] = t1.x; b1a[cb][1] = t1.y; b1a[cb][2] = t1.z; b1a[cb][3] = t1.w;
    w2a[cb][0] = t2.x; w2a[cb][1] = t2.y; w2a[cb][2] = t2.z; w2a[cb][3] = t2.w;
  }
  float rs[8] = {};
#pragma unroll
  for (int cb = 0; cb < 4; ++cb)
#pragma unroll
    for (int rb = 0; rb < 8; ++rb)
#pragma unroll
      for (int r = 0; r < 4; ++r) {
        float v = acc[cb][rb][r] + b1a[cb][r];
        v = v > 0.f ? v : 0.f;
        rs[rb] += v * w2a[cb][r];
      }
#pragma unroll
  for (int rb = 0; rb < 8; ++rb) {
    rs[rb] += __shfl_xor(rs[rb], 16, 64);
    rs[rb] += __shfl_xor(rs[rb], 32, 64);
  }
  __syncthreads();   // all waves past LDS-buffer reads before red reuse? (red separate; this orders nothing critical but keeps barrier count uniform)
  if (lane < 16)
#pragma unroll
    for (int rb = 0; rb < 8; ++rb)
      red[wn][wm * 128 + rb * 16 + lane] = rs[rb];
  __syncthreads();
  if (tid < 256) {
    float y = red[0][tid] + red[1][tid] + red[2][tid] + red[3][tid] + b2_all[leaf];
    y_leaf[(size_t)(row0 + tid) * 32 + leaf] = y;
  }
}

// ---------------- combine ----------------
__global__ void k_combine(const float* __restrict__ pR, const float* __restrict__ y_leaf,
                          float* __restrict__ out) {
  const int b = blockIdx.x * 256 + threadIdx.x;
  float p[32], y[32];
  const float4* pp = (const float4*)(pR + (size_t)b * 32);
  const float4* yp = (const float4*)(y_leaf + (size_t)b * 32);
#pragma unroll
  for (int i = 0; i < 8; ++i) {
    float4 v = pp[i]; p[i*4] = v.x; p[i*4+1] = v.y; p[i*4+2] = v.z; p[i*4+3] = v.w;
    float4 w = yp[i]; y[i*4] = w.x; y[i*4+1] = w.y; y[i*4+2] = w.z; y[i*4+3] = w.w;
  }
  float o = 0.f;
#pragma unroll
  for (int l = 0; l < 32; ++l) {
    float pr = 1.f;
    int node = 0;
#pragma unroll
    for (int k = 0; k < 5; ++k) {
      const int bit = (l >> (4 - k)) & 1;
      const float pv = p[node];
      pr *= bit ? pv : (1.f - pv);
      node = 2 * node + 1 + bit;
    }
    o += pr * y[l];
  }
  out[b] = o;
}

extern "C" void kernel_launch(void* const* d_in, const int* in_sizes, int n_in,
                              void* d_out, int out_size, void* d_ws, size_t ws_size,
                              hipStream_t stream) {
  (void)in_sizes; (void)n_in; (void)out_size; (void)ws_size;
  const float* x        = (const float*)d_in[0];
  const float* enc_W    = (const float*)d_in[1];
  const float* enc_b    = (const float*)d_in[2];
  const float* in_W1    = (const float*)d_in[3];
  const float* in_b1    = (const float*)d_in[4];
  const float* in_Ww    = (const float*)d_in[5];
  const float* in_bw    = (const float*)d_in[6];
  const float* in_Wb    = (const float*)d_in[7];
  const float* in_bb    = (const float*)d_in[8];
  const float* in_Wbeta = (const float*)d_in[9];
  const float* in_bbeta = (const float*)d_in[10];
  const float* lf_W1    = (const float*)d_in[11];
  const float* lf_b1    = (const float*)d_in[12];
  const float* lf_W2    = (const float*)d_in[13];
  const float* lf_b2    = (const float*)d_in[14];
  float* out = (float*)d_out;

  char* ws = (char*)d_ws;
  f16* x_h     = (f16*)(ws);                 // 4 MB
  f16* emb     = (f16*)(ws + 4194304);       // 4 MB
  f16* encWT   = (f16*)(ws + 8388608);       // 512 KB
  f16* lfW1T   = (f16*)(ws + 8912896);       // 4 MB
  f16* inW1T   = (f16*)(ws + 13107200);      // 31*64*256*2 = 1015808
  f16* WwE     = (f16*)(ws + 14123008);      // 31*272*64*2 = 1079296
  float* pR    = (float*)(ws + 15202304);    // 1 MB
  float* y_leaf= (float*)(ws + 16250880);    // 1 MB

  dim3 tb(32, 8);
  hipLaunchKernelGGL(k_cast_f16, dim3(2048), dim3(256), 0, stream, x, x_h, B_ROWS * 256 / 4);
  hipLaunchKernelGGL(k_tcast, dim3(8, 8, 4),  tb, 0, stream, enc_W, encWT, 256, 256, 256, 256);
  hipLaunchKernelGGL(k_tcast, dim3(8, 8, 32), tb, 0, stream, lf_W1, lfW1T, 256, 256, 256, 256);
  hipLaunchKernelGGL(k_tcast, dim3(8, 2, 31), tb, 0, stream, in_W1, inW1T, 256, 50, 256, 64);
  hipLaunchKernelGGL(k_prep_ww, dim3(31), dim3(256), 0, stream, in_Ww, in_Wb, in_Wbeta, WwE);

  hipLaunchKernelGGL(k_enc4, dim3(256), dim3(256), 0, stream, x, encWT, enc_b, emb);
  hipLaunchKernelGGL(k_inner, dim3(128, 8), dim3(256), 0, stream, emb, inW1T, in_b1,
                     WwE, x_h, in_bw, in_bb, in_bbeta, pR);
  hipLaunchKernelGGL(k_leaf, dim3(32, 32), dim3(512), 0, stream, emb, lfW1T, lf_b1, lf_W2, lf_b2, y_leaf);
  hipLaunchKernelGGL(k_combine, dim3(32), dim3(256), 0, stream, pR, y_leaf, out);
}

// Round 8
// 211.032 us; speedup vs baseline: 1.7861x; 1.0183x over previous
//
#include <hip/hip_runtime.h>

// TreeModel: soft decision tree forward. B=8192, D=E=256, H=50 (pad 64),
// 31 inner nodes, 32 leaves. MFMA fp16 16x16x32, fp32 accum/epilogues.

#define B_ROWS 8192
#define HDIM 50
#define HPAD 64
#define LOG2E 1.44269504f

typedef _Float16 f16;
typedef _Float16 f16x8 __attribute__((ext_vector_type(8)));
typedef _Float16 f16x4 __attribute__((ext_vector_type(4)));
typedef float f32x4 __attribute__((ext_vector_type(4)));

static __device__ __forceinline__ f32x4 mfma16(f16x8 a, f16x8 b, f32x4 c) {
  // D[i][j] += sum_k a_frag[i][k] * b_frag[j][k]; i = grp*4+reg, j = lid.
  return __builtin_amdgcn_mfma_f32_16x16x32_f16(a, b, c, 0, 0, 0);
}

// async global->LDS, 16B per lane; lds base must be wave-uniform.
static __device__ __forceinline__ void gload16(const void* g, void* l) {
  __builtin_amdgcn_global_load_lds(
      (const __attribute__((address_space(1))) unsigned int*)g,
      (__attribute__((address_space(3))) unsigned int*)l, 16, 0, 0);
}

// ---------------- merged prep kernel (role-decoded) ----------------
// roles: [0,1024) cast x->f16 ; [1024,3072) tcast lfW1T ; [3072,3328) tcast encW
//        [3328,3824) tcast inW1T ; [3824,3855) build WwE (Ww scaled by log2e)
static __device__ __forceinline__ void tcast_body(const float* ip, f16* op,
    int R, int C, int Rp, int r0, int c0, int tx, int ty, float scale,
    float t[32][33]) {
#pragma unroll
  for (int i = 0; i < 4; ++i) {
    int r = r0 + ty + 8 * i, c = c0 + tx;
    t[ty + 8 * i][tx] = (r < R && c < C) ? ip[(size_t)r * C + c] * scale : 0.f;
  }
  __syncthreads();
#pragma unroll
  for (int i = 0; i < 4; ++i) {
    int c = c0 + ty + 8 * i, r = r0 + tx;
    op[(size_t)c * Rp + r] = (f16)t[tx][ty + 8 * i];
  }
}

__global__ __launch_bounds__(256) void k_prep(
    const float* __restrict__ x, const float* __restrict__ enc_W,
    const float* __restrict__ lf_W1, const float* __restrict__ in_W1,
    const float* __restrict__ in_Ww, const float* __restrict__ in_Wb,
    const float* __restrict__ in_Wbeta,
    f16* __restrict__ x_h, f16* __restrict__ encWT, f16* __restrict__ lfW1T,
    f16* __restrict__ inW1T, f16* __restrict__ WwE) {
  __shared__ float t[32][33];
  const int idx = blockIdx.x;
  const int tid = threadIdx.x;
  if (idx < 1024) {
    // cast x -> f16, 2048 elems per block
    const int e8 = idx * 256 + tid;  // f16x8 index
    const float4* f4 = (const float4*)x;
    float4 v0 = f4[e8 * 2], v1 = f4[e8 * 2 + 1];
    f16x8 o = { (f16)v0.x, (f16)v0.y, (f16)v0.z, (f16)v0.w,
                (f16)v1.x, (f16)v1.y, (f16)v1.z, (f16)v1.w };
    ((f16x8*)x_h)[e8] = o;
  } else if (idx < 3072) {
    const int q = idx - 1024;                      // lfW1T: (8,8,32)
    const int s = q >> 6, bx = (q & 63) >> 3, by = q & 7;
    tcast_body(lf_W1 + (size_t)s * 65536, lfW1T + (size_t)s * 65536,
               256, 256, 256, bx * 32, by * 32, tid & 31, tid >> 5, 1.f, t);
  } else if (idx < 3328) {
    const int q = idx - 3072;                      // encW: (8,8,4)
    const int s = q >> 6, bx = (q & 63) >> 3, by = q & 7;
    tcast_body(enc_W + (size_t)s * 65536, encWT + (size_t)s * 65536,
               256, 256, 256, bx * 32, by * 32, tid & 31, tid >> 5, 1.f, t);
  } else if (idx < 3824) {
    const int q = idx - 3328;                      // inW1T: (8,2,31)
    const int s = q >> 4, bx = (q & 15) >> 1, by = q & 1;
    tcast_body(in_W1 + (size_t)s * 256 * HDIM, inW1T + (size_t)s * HPAD * 256,
               256, HDIM, 256, bx * 32, by * 32, tid & 31, tid >> 5, 1.f, t);
  } else {
    // WwE[272][64]: rows 0..255 = log2e * Ww^T (pad h>=50 with 0);
    // row 256 = Wb, row 257 = Wbeta (unscaled), 258..271 = 0.
    const int node = idx - 3824;
    const int d = tid;
    f16 row[64];
#pragma unroll
    for (int h = 0; h < 64; ++h)
      row[h] = (h < HDIM) ? (f16)(in_Ww[((size_t)node * HDIM + h) * 256 + d] * LOG2E)
                          : (f16)0.f;
    f16* dst = WwE + (size_t)node * 272 * 64 + (size_t)d * 64;
#pragma unroll
    for (int j = 0; j < 8; ++j) *(f16x8*)&dst[j * 8] = *(const f16x8*)&row[j * 8];
    if (d < 16) {
      f16 er[64];
#pragma unroll
      for (int h = 0; h < 64; ++h) {
        float v = 0.f;
        if (d == 0 && h < HDIM) v = in_Wb[node * HDIM + h];
        if (d == 1 && h < HDIM) v = in_Wbeta[node * HDIM + h];
        er[h] = (f16)v;
      }
      f16* dst2 = WwE + (size_t)node * 272 * 64 + (size_t)(256 + d) * 64;
#pragma unroll
      for (int j = 0; j < 8; ++j) *(f16x8*)&dst2[j * 8] = *(const f16x8*)&er[j * 8];
    }
  }
}

// ---------------- fused 4-layer encoder (unchanged) ----------------
__global__ __launch_bounds__(256) void k_enc4(const float* __restrict__ x,
    const f16* __restrict__ encWT, const float* __restrict__ enc_b,
    f16* __restrict__ emb) {
  __shared__ f16 act[2][32][264];
  __shared__ f16 Bt[256][72];
  const int tid = threadIdx.x;
  const int wave = tid >> 6, lane = tid & 63;
  const int grp = lane >> 4, lid = lane & 15;
  const int row0 = blockIdx.x * 32;
  const int sr = tid >> 3, sc = (tid & 7) * 8;

  {
    const int xr = tid >> 3, xc = (tid & 7) * 32;
    const float* src = x + (size_t)(row0 + xr) * 256 + xc;
#pragma unroll
    for (int j = 0; j < 4; ++j) {
      float4 a = ((const float4*)src)[2 * j];
      float4 b = ((const float4*)src)[2 * j + 1];
      f16x8 o = { (f16)a.x, (f16)a.y, (f16)a.z, (f16)a.w,
                  (f16)b.x, (f16)b.y, (f16)b.z, (f16)b.w };
      *(f16x8*)&act[0][xr][xc + 8 * j] = o;
    }
  }
  __syncthreads();

  for (int l = 0; l < 4; ++l) {
    const int cur = l & 1, nxt = cur ^ 1;
    f32x4 acc[2][4] = {};
    for (int kt = 0; kt < 4; ++kt) {
#pragma unroll
      for (int p = 0; p < 8; ++p)
        *(f16x8*)&Bt[p * 32 + sr][sc] =
            *(const f16x8*)&encWT[(size_t)l * 65536 + (size_t)(p * 32 + sr) * 256 + kt * 64 + sc];
      __syncthreads();
#pragma unroll
      for (int kk = 0; kk < 2; ++kk) {
        f16x8 af[2], bf[4];
#pragma unroll
        for (int m = 0; m < 2; ++m)
          af[m] = *(const f16x8*)&act[cur][m * 16 + lid][kt * 64 + kk * 32 + grp * 8];
#pragma unroll
        for (int n = 0; n < 4; ++n)
          bf[n] = *(const f16x8*)&Bt[wave * 64 + n * 16 + lid][kk * 32 + grp * 8];
#pragma unroll
        for (int m = 0; m < 2; ++m)
#pragma unroll
          for (int n = 0; n < 4; ++n) acc[m][n] = mfma16(af[m], bf[n], acc[m][n]);
      }
      __syncthreads();
    }
#pragma unroll
    for (int n = 0; n < 4; ++n) {
      const int col = wave * 64 + n * 16 + lid;
      const float bv = enc_b[l * 256 + col];
#pragma unroll
      for (int m = 0; m < 2; ++m)
#pragma unroll
        for (int r = 0; r < 4; ++r) {
          float v = acc[m][n][r] + bv;
          act[nxt][m * 16 + grp * 4 + r][col] = (f16)(v > 0.f ? v : 0.f);
        }
    }
    __syncthreads();
  }
  {
    const int xr = tid >> 3, xc = (tid & 7) * 32;
#pragma unroll
    for (int j = 0; j < 4; ++j)
      *(f16x8*)&emb[(size_t)(row0 + xr) * 256 + xc + 8 * j] =
          *(const f16x8*)&act[0][xr][xc + 8 * j];
  }
}

// ---------------- fused inner nodes: wave-private node, ILP-deepened -------
// Grid (8 node-quads [fast axis -> XCD locality], 128 row-tiles).
// h fragments hoisted to regs (reused mini + 4 chunks); chunk weights
// double-buffered; softmax via exp2 (WwE pre-scaled by log2e).
__global__ __launch_bounds__(256, 2) void k_inner(const f16* __restrict__ emb,
    const f16* __restrict__ W1T_all, const float* __restrict__ b1_all,
    const f16* __restrict__ WwE_all, const f16* __restrict__ x_h,
    const float* __restrict__ bw_all, const float* __restrict__ bb_all,
    const float* __restrict__ bbeta_all, float* __restrict__ pR) {
  __shared__ f16 et[64][264];            // emb tile, then x tile (reused)
  __shared__ f16 hbuf[4][64][72];        // wave-private h (batch-major)

  const int tid = threadIdx.x;
  const int wave = tid >> 6, lane = tid & 63;
  const int grp = lane >> 4, lid = lane & 15;
  const int row0 = blockIdx.y * 64;
  const int node_raw = blockIdx.x * 4 + wave;
  const int node = node_raw < 31 ? node_raw : 30;

  // cooperative emb stage
  {
    const int r = tid >> 2, cb = (tid & 3) * 64;
#pragma unroll
    for (int j = 0; j < 8; ++j)
      *(f16x8*)&et[r][cb + 8 * j] =
          *(const f16x8*)&emb[(size_t)(row0 + r) * 256 + cb + 8 * j];
  }
  __syncthreads();

  const f16* W1T = W1T_all + (size_t)node * HPAD * 256;   // [64][256]
  const f16* WwE = WwE_all + (size_t)node * 272 * 64;     // [272][64]

  // ---- GEMM1: h^T = W1^T emb^T, 64 hdim x 64 batch, K=256 ----
  f32x4 acc1[4][4] = {};   // [h4][m]
  f16x8 wf[2][4];
#pragma unroll
  for (int h4 = 0; h4 < 4; ++h4)
    wf[0][h4] = *(const f16x8*)&W1T[(size_t)(h4 * 16 + lid) * 256 + grp * 8];
  for (int kt = 0; kt < 8; ++kt) {
    const int cur = kt & 1, nxt = cur ^ 1;
    if (kt < 7) {
#pragma unroll
      for (int h4 = 0; h4 < 4; ++h4)
        wf[nxt][h4] = *(const f16x8*)&W1T[(size_t)(h4 * 16 + lid) * 256 +
                                          (kt + 1) * 32 + grp * 8];
    }
    f16x8 af[4];
#pragma unroll
    for (int m = 0; m < 4; ++m)
      af[m] = *(const f16x8*)&et[m * 16 + lid][kt * 32 + grp * 8];
#pragma unroll
    for (int h4 = 0; h4 < 4; ++h4)
#pragma unroll
      for (int m = 0; m < 4; ++m)
        acc1[h4][m] = mfma16(wf[cur][h4], af[m], acc1[h4][m]);
  }
  // h epilogue -> wave-private LDS, batch-major [64][72]
#pragma unroll
  for (int h4 = 0; h4 < 4; ++h4) {
    const int hc = h4 * 16 + grp * 4;
    float bva[4];
#pragma unroll
    for (int r = 0; r < 4; ++r)
      bva[r] = (hc + r < HDIM) ? b1_all[node * HDIM + hc + r] : 0.f;
#pragma unroll
    for (int m = 0; m < 4; ++m) {
      f16x4 hv;
#pragma unroll
      for (int r = 0; r < 4; ++r) {
        float v = acc1[h4][m][r] + bva[r];
        hv[r] = (f16)(v > 0.f ? v : 0.f);
      }
      *(f16x4*)&hbuf[wave][m * 16 + lid][hc] = hv;
    }
  }
  __syncthreads();   // all waves done reading et
  // stage x tile into et region
  {
    const int r = tid >> 2, cb = (tid & 3) * 64;
#pragma unroll
    for (int j = 0; j < 8; ++j)
      *(f16x8*)&et[r][cb + 8 * j] =
          *(const f16x8*)&x_h[(size_t)(row0 + r) * 256 + cb + 8 * j];
  }
  __syncthreads();

  // hoist h fragments to registers (reused by mini-MFMA + all 4 chunks)
  f16x8 hf[2][4];
#pragma unroll
  for (int kk = 0; kk < 2; ++kk)
#pragma unroll
    for (int m = 0; m < 4; ++m)
      hf[kk][m] = *(const f16x8*)&hbuf[wave][m * 16 + lid][kk * 32 + grp * 8];

  // mini-MFMA: b/beta dots (WwE rows 256..271, unscaled)
  f32x4 accm[4] = {};
  {
    f16x8 wm0 = *(const f16x8*)&WwE[(size_t)(256 + lid) * 64 + grp * 8];
    f16x8 wm1 = *(const f16x8*)&WwE[(size_t)(256 + lid) * 64 + 32 + grp * 8];
#pragma unroll
    for (int m = 0; m < 4; ++m) {
      accm[m] = mfma16(wm0, hf[0][m], accm[m]);
      accm[m] = mfma16(wm1, hf[1][m], accm[m]);
    }
  }

#define LOADW(buf, c)                                                          \
  _Pragma("unroll")                                                            \
  for (int kk = 0; kk < 2; ++kk)                                               \
    _Pragma("unroll")                                                          \
    for (int n4 = 0; n4 < 4; ++n4)                                             \
      buf[kk][n4] = *(const f16x8*)&WwE[(size_t)((c) * 64 + n4 * 16 + lid) * 64 + \
                                        kk * 32 + grp * 8];

#define CHUNK(c, CUR)                                                          \
  {                                                                            \
    f32x4 acc2[4][4] = {};                                                     \
    _Pragma("unroll")                                                          \
    for (int kk = 0; kk < 2; ++kk)                                             \
      _Pragma("unroll")                                                        \
      for (int n4 = 0; n4 < 4; ++n4)                                           \
        _Pragma("unroll")                                                      \
        for (int m = 0; m < 4; ++m)                                            \
          acc2[n4][m] = mfma16(CUR[kk][n4], hf[kk][m], acc2[n4][m]);           \
    _Pragma("unroll")                                                          \
    for (int n4 = 0; n4 < 4; ++n4) {                                           \
      float4 bwv = *(const float4*)&bw_all[node * 256 + (c) * 64 + n4 * 16 + grp * 4]; \
      float bwa[4] = {bwv.x * LOG2E, bwv.y * LOG2E, bwv.z * LOG2E, bwv.w * LOG2E}; \
      _Pragma("unroll")                                                        \
      for (int m = 0; m < 4; ++m) {                                            \
        f16x4 xv = *(const f16x4*)&et[m * 16 + lid][(c) * 64 + n4 * 16 + grp * 4]; \
        _Pragma("unroll")                                                      \
        for (int r = 0; r < 4; ++r) {                                          \
          float e = exp2f(acc2[n4][m][r] + bwa[r]);                            \
          s[m] += e;                                                           \
          dt[m] += e * (float)xv[r];                                           \
        }                                                                      \
      }                                                                        \
    }                                                                          \
  }

  float s[4] = {0.f, 0.f, 0.f, 0.f}, dt[4] = {0.f, 0.f, 0.f, 0.f};
  f16x8 awfA[2][4], awfB[2][4];
  LOADW(awfA, 0);
  LOADW(awfB, 1);
  CHUNK(0, awfA);
  LOADW(awfA, 2);
  CHUNK(1, awfB);
  LOADW(awfB, 3);
  CHUNK(2, awfA);
  CHUNK(3, awfB);
#undef LOADW
#undef CHUNK

  // reduce over grp
#pragma unroll
  for (int m = 0; m < 4; ++m) {
    s[m]  += __shfl_xor(s[m], 16, 64);  s[m]  += __shfl_xor(s[m], 32, 64);
    dt[m] += __shfl_xor(dt[m], 16, 64); dt[m] += __shfl_xor(dt[m], 32, 64);
  }
  if (grp == 0 && node_raw < 31) {
    const float bbv = bb_all[node], bbetav = bbeta_all[node];
#pragma unroll
    for (int m = 0; m < 4; ++m) {
      const int row = m * 16 + lid;
      float b = accm[m][0] + bbv;
      float beta = accm[m][1] + bbetav;
      float z = beta * (dt[m] / s[m] + b);
      pR[(size_t)(row0 + row) * 32 + node] = 1.f / (1.f + __expf(-z));
    }
  }
}

// ---------------- leaf: 8-wave, 256 rows x 256 cols, dbuf pipeline ----------
// Grid (32 leaves [fast axis -> XCD locality], 32 row-tiles).
__global__ __launch_bounds__(512) void k_leaf(const f16* __restrict__ emb,
    const f16* __restrict__ W1T_all, const float* __restrict__ b1_all,
    const float* __restrict__ W2_all, const float* __restrict__ b2_all,
    float* __restrict__ y_leaf) {
  __shared__ f16 Albuf[2][256 * 64];
  __shared__ f16 Blbuf[2][256 * 64];
  __shared__ float red[4][256];
  const int tid = threadIdx.x;
  const int wave = tid >> 6, lane = tid & 63;
  const int wm = wave >> 2, wn = wave & 3;
  const int grp = lane >> 4, lid = lane & 15;
  const int row0 = blockIdx.y * 256;
  const int leaf = blockIdx.x;
  const f16* WT = W1T_all + (size_t)leaf * 65536;
  const float* b1 = b1_all + leaf * 256;
  const float* W2 = W2_all + leaf * 256;

  const int lrow = lane >> 3;
  const int sslot = (lane & 7) ^ lrow;
  const int swzA = (lid & 7);

#define LEAF_STAGE(buf, kt)                                                    \
  {                                                                            \
    _Pragma("unroll")                                                          \
    for (int r4 = 0; r4 < 4; ++r4) {                                           \
      const int rr = r4 * 64 + wave * 8 + lrow;                                \
      gload16(emb + (size_t)(row0 + rr) * 256 + (kt) * 64 + sslot * 8,         \
              (char*)&Albuf[buf][0] + r4 * 8192 + wave * 1024);                \
      gload16(WT + (size_t)rr * 256 + (kt) * 64 + sslot * 8,                   \
              (char*)&Blbuf[buf][0] + r4 * 8192 + wave * 1024);                \
    }                                                                          \
  }

  f32x4 acc[4][8] = {};
  LEAF_STAGE(0, 0);
  __syncthreads();
  for (int kt = 0; kt < 4; ++kt) {
    const int b = kt & 1;
    if (kt < 3) LEAF_STAGE(b ^ 1, kt + 1);
#pragma unroll
    for (int kk = 0; kk < 2; ++kk) {
      f16x8 af[8], bf[4];
#pragma unroll
      for (int rb = 0; rb < 8; ++rb) {
        const int row = wm * 128 + rb * 16 + lid;
        af[rb] = *(const f16x8*)((const char*)&Albuf[b][0] + row * 128 +
                                 (((kk * 4 + grp) ^ swzA) << 4));
      }
#pragma unroll
      for (int cb = 0; cb < 4; ++cb) {
        const int col = wn * 64 + cb * 16 + lid;
        bf[cb] = *(const f16x8*)((const char*)&Blbuf[b][0] + col * 128 +
                                 (((kk * 4 + grp) ^ swzA) << 4));
      }
#pragma unroll
      for (int cb = 0; cb < 4; ++cb)
#pragma unroll
        for (int rb = 0; rb < 8; ++rb)
          acc[cb][rb] = mfma16(bf[cb], af[rb], acc[cb][rb]);
    }
    if (kt < 3) __syncthreads();
  }
#undef LEAF_STAGE
  float b1a[4][4], w2a[4][4];
#pragma unroll
  for (int cb = 0; cb < 4; ++cb) {
    float4 t1 = *(const float4*)&b1[wn * 64 + cb * 16 + grp * 4];
    float4 t2 = *(const float4*)&W2[wn * 64 + cb * 16 + grp * 4];
    b1a[cb][0] = t1.x; b1a[cb][1] = t1.y; b1a[cb][2] = t1.z; b1a[cb][3] = t1.w;
    w2a[cb][0] = t2.x; w2a[cb][1] = t2.y; w2a[cb][2] = t2.z; w2a[cb][3] = t2.w;
  }
  float rs[8] = {};
#pragma unroll
  for (int cb = 0; cb < 4; ++cb)
#pragma unroll
    for (int rb = 0; rb < 8; ++rb)
#pragma unroll
      for (int r = 0; r < 4; ++r) {
        float v = acc[cb][rb][r] + b1a[cb][r];
        v = v > 0.f ? v : 0.f;
        rs[rb] += v * w2a[cb][r];
      }
#pragma unroll
  for (int rb = 0; rb < 8; ++rb) {
    rs[rb] += __shfl_xor(rs[rb], 16, 64);
    rs[rb] += __shfl_xor(rs[rb], 32, 64);
  }
  __syncthreads();
  if (lane < 16)
#pragma unroll
    for (int rb = 0; rb < 8; ++rb)
      red[wn][wm * 128 + rb * 16 + lane] = rs[rb];
  __syncthreads();
  if (tid < 256) {
    float y = red[0][tid] + red[1][tid] + red[2][tid] + red[3][tid] + b2_all[leaf];
    y_leaf[(size_t)(row0 + tid) * 32 + leaf] = y;
  }
}

// ---------------- combine ----------------
__global__ void k_combine(const float* __restrict__ pR, const float* __restrict__ y_leaf,
                          float* __restrict__ out) {
  const int b = blockIdx.x * 256 + threadIdx.x;
  float p[32], y[32];
  const float4* pp = (const float4*)(pR + (size_t)b * 32);
  const float4* yp = (const float4*)(y_leaf + (size_t)b * 32);
#pragma unroll
  for (int i = 0; i < 8; ++i) {
    float4 v = pp[i]; p[i*4] = v.x; p[i*4+1] = v.y; p[i*4+2] = v.z; p[i*4+3] = v.w;
    float4 w = yp[i]; y[i*4] = w.x; y[i*4+1] = w.y; y[i*4+2] = w.z; y[i*4+3] = w.w;
  }
  float o = 0.f;
#pragma unroll
  for (int l = 0; l < 32; ++l) {
    float pr = 1.f;
    int node = 0;
#pragma unroll
    for (int k = 0; k < 5; ++k) {
      const int bit = (l >> (4 - k)) & 1;
      const float pv = p[node];
      pr *= bit ? pv : (1.f - pv);
      node = 2 * node + 1 + bit;
    }
    o += pr * y[l];
  }
  out[b] = o;
}

extern "C" void kernel_launch(void* const* d_in, const int* in_sizes, int n_in,
                              void* d_out, int out_size, void* d_ws, size_t ws_size,
                              hipStream_t stream) {
  (void)in_sizes; (void)n_in; (void)out_size; (void)ws_size;
  const float* x        = (const float*)d_in[0];
  const float* enc_W    = (const float*)d_in[1];
  const float* enc_b    = (const float*)d_in[2];
  const float* in_W1    = (const float*)d_in[3];
  const float* in_b1    = (const float*)d_in[4];
  const float* in_Ww    = (const float*)d_in[5];
  const float* in_bw    = (const float*)d_in[6];
  const float* in_Wb    = (const float*)d_in[7];
  const float* in_bb    = (const float*)d_in[8];
  const float* in_Wbeta = (const float*)d_in[9];
  const float* in_bbeta = (const float*)d_in[10];
  const float* lf_W1    = (const float*)d_in[11];
  const float* lf_b1    = (const float*)d_in[12];
  const float* lf_W2    = (const float*)d_in[13];
  const float* lf_b2    = (const float*)d_in[14];
  float* out = (float*)d_out;

  char* ws = (char*)d_ws;
  f16* x_h     = (f16*)(ws);                 // 4 MB
  f16* emb     = (f16*)(ws + 4194304);       // 4 MB
  f16* encWT   = (f16*)(ws + 8388608);       // 512 KB
  f16* lfW1T   = (f16*)(ws + 8912896);       // 4 MB
  f16* inW1T   = (f16*)(ws + 13107200);      // 31*64*256*2
  f16* WwE     = (f16*)(ws + 14123008);      // 31*272*64*2
  float* pR    = (float*)(ws + 15202304);    // 1 MB
  float* y_leaf= (float*)(ws + 16250880);    // 1 MB

  hipLaunchKernelGGL(k_prep, dim3(3855), dim3(256), 0, stream,
                     x, enc_W, lf_W1, in_W1, in_Ww, in_Wb, in_Wbeta,
                     x_h, encWT, lfW1T, inW1T, WwE);
  hipLaunchKernelGGL(k_enc4, dim3(256), dim3(256), 0, stream, x, encWT, enc_b, emb);
  hipLaunchKernelGGL(k_inner, dim3(8, 128), dim3(256), 0, stream, emb, inW1T, in_b1,
                     WwE, x_h, in_bw, in_bb, in_bbeta, pR);
  hipLaunchKernelGGL(k_leaf, dim3(32, 32), dim3(512), 0, stream, emb, lfW1T, lf_b1, lf_W2, lf_b2, y_leaf);
  hipLaunchKernelGGL(k_combine, dim3(32), dim3(256), 0, stream, pR, y_leaf, out);
}